// Round 2
// baseline (4894.759 us; speedup 1.0000x reference)
//
#include <hip/hip_runtime.h>
#include <hip/hip_fp16.h>

#define NH 4
#define HD 64
#define MF 266
#define NBCTX 128
#define DN 0.35355339059327373f
#define RATIO 0.06131393394849658f
#define EPSRF 1e-4f

typedef unsigned short u16;
typedef unsigned int u32;

__device__ __forceinline__ float bf2f(u16 u){ return __uint_as_float(((u32)u)<<16); }
__device__ __forceinline__ u16 f2bf(float f){ u32 u = __float_as_uint(f); u += 0x7FFFu + ((u>>16)&1u); return (u16)(u>>16); }
__device__ __forceinline__ float eluf(float x){ return x>0.f ? x : (expf(x)-1.f); }

// ---------------- K1: fused projection GEMM: [N,256] @ [256,1024]^T ----------------
// col 0..255->Q, 256..511->K, 512..767->V, 768..1023->gnn1. Q/K/V head-major bf16.
__global__ __launch_bounds__(256) void k_proj(
    const float* __restrict__ x,
    const float* __restrict__ qw, const float* __restrict__ kw,
    const float* __restrict__ vw, const float* __restrict__ lw,
    const float* __restrict__ qb, const float* __restrict__ kb,
    const float* __restrict__ vb, const float* __restrict__ lb,
    u16* __restrict__ Q, u16* __restrict__ K, u16* __restrict__ V,
    u16* __restrict__ G1, int n)
{
  __shared__ float As[16][68];
  __shared__ float Bs[16][68];
  const int tid = threadIdx.x;
  const int row0 = blockIdx.x*64;
  const int col0 = blockIdx.y*64;
  const int sel = col0>>8;
  const float* wsel = sel==0?qw : sel==1?kw : sel==2?vw : lw;
  const float* bsel = sel==0?qb : sel==1?kb : sel==2?vb : lb;
  u16* dsel = sel==0?Q : sel==1?K : sel==2?V : G1;
  const int tx = tid&15, ty = tid>>4;
  const int lr = tid>>2, lk = (tid&3)*4;
  float acc[4][4] = {};
  for (int kt=0; kt<16; ++kt){
    const int k0 = kt*16;
    float4 av = make_float4(0.f,0.f,0.f,0.f);
    if (row0+lr < n) av = *(const float4*)(x + (size_t)(row0+lr)*256 + k0 + lk);
    float4 bv = *(const float4*)(wsel + (size_t)((col0&255)+lr)*256 + k0 + lk);
    __syncthreads();
    As[lk+0][lr]=av.x; As[lk+1][lr]=av.y; As[lk+2][lr]=av.z; As[lk+3][lr]=av.w;
    Bs[lk+0][lr]=bv.x; Bs[lk+1][lr]=bv.y; Bs[lk+2][lr]=bv.z; Bs[lk+3][lr]=bv.w;
    __syncthreads();
    #pragma unroll
    for (int kk=0; kk<16; ++kk){
      float4 a4 = *(const float4*)&As[kk][ty*4];
      float4 b4 = *(const float4*)&Bs[kk][tx*4];
      float a_[4] = {a4.x,a4.y,a4.z,a4.w};
      float b_[4] = {b4.x,b4.y,b4.z,b4.w};
      #pragma unroll
      for (int i=0;i<4;i++)
        #pragma unroll
        for (int j=0;j<4;j++) acc[i][j] += a_[i]*b_[j];
    }
  }
  #pragma unroll
  for (int i=0;i<4;i++){
    const int r = row0 + ty*4 + i;
    if (r >= n) continue;
    #pragma unroll
    for (int j=0;j<4;j++){
      const int cc = (col0&255) + tx*4 + j;
      float v = acc[i][j] + bsel[cc];
      u16 bvv = f2bf(v);
      if (sel==3) dsel[(size_t)r*256 + cc] = bvv;
      else { int hh = cc>>6, dd = cc&63; dsel[(((size_t)hh*n + r)<<6) + dd] = bvv; }
    }
  }
}

// ---------------- K2: global max of key data_dash per head ----------------
__global__ __launch_bounds__(256) void k_kmax(
    const u16* __restrict__ K, const float* __restrict__ proj,
    u32* __restrict__ kmaxg, int n)
{
  __shared__ float As[64][68];
  __shared__ float Bs[64][68];
  __shared__ float red[256];
  const int tid = threadIdx.x;
  const int h = blockIdx.y;
  const int node0 = blockIdx.x*64;
  const int tx = tid&15, ty = tid>>4;
  #pragma unroll
  for (int q=0;q<2;q++){
    int e8 = tid + q*256;
    int nn = e8>>3, d0 = (e8&7)*8;
    uint4 raw = make_uint4(0,0,0,0);
    if (node0+nn < n) raw = *(const uint4*)(K + (((size_t)h*n + node0+nn)<<6) + d0);
    const u16* p = (const u16*)&raw;
    #pragma unroll
    for (int s=0;s<8;s++) As[d0+s][nn] = bf2f(p[s]);
  }
  float mx = -3.0e38f;
  #pragma unroll 1
  for (int mc=0; mc<5; ++mc){
    __syncthreads();
    #pragma unroll
    for (int q=0;q<4;q++){
      int fl = tid + q*256;
      int ml = fl>>4, dq = (fl&15)*4;
      int m = mc*64 + ml;
      float4 pv = make_float4(0.f,0.f,0.f,0.f);
      if (m < MF) pv = *(const float4*)(proj + (size_t)m*64 + dq);
      Bs[dq+0][ml]=pv.x; Bs[dq+1][ml]=pv.y; Bs[dq+2][ml]=pv.z; Bs[dq+3][ml]=pv.w;
    }
    __syncthreads();
    float acc[4][4] = {};
    #pragma unroll 4
    for (int d=0; d<64; ++d){
      float4 a4 = *(const float4*)&As[d][ty*4];
      float4 b4 = *(const float4*)&Bs[d][tx*4];
      float a_[4] = {a4.x,a4.y,a4.z,a4.w};
      float b_[4] = {b4.x,b4.y,b4.z,b4.w};
      #pragma unroll
      for (int i=0;i<4;i++)
        #pragma unroll
        for (int j=0;j<4;j++) acc[i][j] += a_[i]*b_[j];
    }
    #pragma unroll
    for (int i=0;i<4;i++)
      #pragma unroll
      for (int j=0;j<4;j++){
        int nn = ty*4+i, m = mc*64+tx*4+j;
        if (node0+nn<n && m<MF) mx = fmaxf(mx, acc[i][j]);
      }
  }
  red[tid] = mx; __syncthreads();
  for (int off=128; off; off>>=1){
    if (tid<off) red[tid] = fmaxf(red[tid], red[tid+off]);
    __syncthreads();
  }
  if (tid==0){
    float f = red[0]*DN;
    u32 b = __float_as_uint(f);
    u32 enc = (b & 0x80000000u) ? ~b : (b | 0x80000000u);
    atomicMax(kmaxg + h, enc);
  }
}

// ---------------- K3: per-(head, m-chunk) kp -> k_sum + context partials ----------------
__global__ __launch_bounds__(256) void k_ctx(
    const u16* __restrict__ K, const u16* __restrict__ V,
    const float* __restrict__ proj, const u32* __restrict__ kmaxg,
    float* __restrict__ ctxp, float* __restrict__ ksump, int n)
{
  __shared__ float As[64][68];   // K^T tile: As[d][node]
  __shared__ u16  Vt[64][72];    // V tile:   Vt[node][d] (raw bf16)
  __shared__ float kp_s[64][68]; // kp chunk: kp_s[node][ml]
  __shared__ float Bs[64][68];   // proj^T chunk: Bs[d][ml]
  __shared__ float diag[64];
  const int tid = threadIdx.x;
  const int h = blockIdx.y / 5, mc = blockIdx.y % 5;
  const int bb = blockIdx.x;
  const int tx = tid&15, ty = tid>>4;
  float mxh; { u32 ee = kmaxg[h]; u32 b = (ee & 0x80000000u) ? (ee ^ 0x80000000u) : ~ee; mxh = __uint_as_float(b); }
  // load proj chunk once (constant for this block)
  #pragma unroll
  for (int q=0;q<4;q++){
    int fl = tid + q*256;
    int ml = fl>>4, dq = (fl&15)*4;
    int m = mc*64 + ml;
    float4 pv = make_float4(0.f,0.f,0.f,0.f);
    if (m < MF) pv = *(const float4*)(proj + (size_t)m*64 + dq);
    Bs[dq+0][ml]=pv.x; Bs[dq+1][ml]=pv.y; Bs[dq+2][ml]=pv.z; Bs[dq+3][ml]=pv.w;
  }
  float acc2[16] = {};
  float ksa = 0.f;
  const int ntile = (n+63)>>6;
  #pragma unroll 1
  for (int t = bb; t < ntile; t += NBCTX){
    const int node0 = t*64;
    __syncthreads();
    #pragma unroll
    for (int q=0;q<2;q++){
      int e8 = tid + q*256;
      int nn = e8>>3, d0 = (e8&7)*8;
      uint4 rk = make_uint4(0,0,0,0), rv = make_uint4(0,0,0,0);
      if (node0+nn < n){
        rk = *(const uint4*)(K + (((size_t)h*n + node0+nn)<<6) + d0);
        rv = *(const uint4*)(V + (((size_t)h*n + node0+nn)<<6) + d0);
      }
      const u16* pk = (const u16*)&rk;
      #pragma unroll
      for (int s=0;s<8;s++) As[d0+s][nn] = bf2f(pk[s]);
      *(uint4*)&Vt[nn][d0] = rv;
    }
    __syncthreads();
    if (tid < 64){
      float s = 0.f;
      #pragma unroll 8
      for (int d=0; d<64; ++d){ float v = As[d][tid]; s += v*v; }
      diag[tid] = 0.0625f*s;
    }
    __syncthreads();
    float acc[4][4] = {};
    #pragma unroll 4
    for (int d=0; d<64; ++d){
      float4 a4 = *(const float4*)&As[d][ty*4];
      float4 b4 = *(const float4*)&Bs[d][tx*4];
      float a_[4] = {a4.x,a4.y,a4.z,a4.w};
      float b_[4] = {b4.x,b4.y,b4.z,b4.w};
      #pragma unroll
      for (int i=0;i<4;i++)
        #pragma unroll
        for (int j=0;j<4;j++) acc[i][j] += a_[i]*b_[j];
    }
    #pragma unroll
    for (int i=0;i<4;i++)
      #pragma unroll
      for (int j=0;j<4;j++){
        int nn = ty*4+i, m = mc*64+tx*4+j;
        float kp = 0.f;
        if (m<MF && node0+nn<n) kp = RATIO*(expf(DN*acc[i][j] - diag[nn] - mxh) + EPSRF);
        kp_s[nn][tx*4+j] = kp;
      }
    __syncthreads();
    if (tid < 64 && mc*64+tid < MF){
      float s = 0.f;
      #pragma unroll 8
      for (int nn=0; nn<64; ++nn) s += kp_s[nn][tid];
      ksa += s;
    }
    #pragma unroll 4
    for (int nn=0; nn<64; ++nn){
      float4 a4 = *(const float4*)&kp_s[nn][ty*4];
      ushort4 bv = *(const ushort4*)&Vt[nn][tx*4];
      float b0=bf2f(bv.x), b1=bf2f(bv.y), b2=bf2f(bv.z), b3=bf2f(bv.w);
      acc2[0]+=a4.x*b0; acc2[1]+=a4.x*b1; acc2[2]+=a4.x*b2; acc2[3]+=a4.x*b3;
      acc2[4]+=a4.y*b0; acc2[5]+=a4.y*b1; acc2[6]+=a4.y*b2; acc2[7]+=a4.y*b3;
      acc2[8]+=a4.z*b0; acc2[9]+=a4.z*b1; acc2[10]+=a4.z*b2; acc2[11]+=a4.z*b3;
      acc2[12]+=a4.w*b0; acc2[13]+=a4.w*b1; acc2[14]+=a4.w*b2; acc2[15]+=a4.w*b3;
    }
  }
  #pragma unroll
  for (int i=0;i<4;i++){
    int m = mc*64 + ty*4 + i;
    if (m < MF){
      float* dst = ctxp + ((((size_t)h*NBCTX + bb)*MF + m)<<6) + tx*4;
      #pragma unroll
      for (int j=0;j<4;j++) dst[j] = acc2[i*4+j];
    }
  }
  if (tid < 64){
    int m = mc*64 + tid;
    if (m < MF) ksump[((size_t)h*NBCTX + bb)*MF + m] = ksa;
  }
}

// ---------------- K3b: reduce partials ----------------
__global__ void k_reduce(const float* __restrict__ ctxp, const float* __restrict__ ksump,
                         float* __restrict__ ctx, float* __restrict__ ksum)
{
  const int T1 = NH*MF*64;
  int idx = blockIdx.x*256 + threadIdx.x;
  if (idx < T1){
    int h = idx / (MF*64);
    int r = idx - h*MF*64;
    float s = 0.f;
    for (int b=0; b<NBCTX; ++b) s += ctxp[(((size_t)h*NBCTX + b)*MF)*64 + r];
    ctx[(size_t)h*MF*64 + r] = s;
  } else if (idx < T1 + NH*MF){
    int k = idx - T1;
    int h = k / MF, m = k - h*MF;
    float s = 0.f;
    for (int b=0; b<NBCTX; ++b) s += ksump[((size_t)h*NBCTX + b)*MF + m];
    ksum[(size_t)h*MF + m] = s;
  }
}

// ---------------- K4: query path -> attention output (trans) ----------------
__global__ __launch_bounds__(256) void k_qattn(
    const u16* __restrict__ Q, const float* __restrict__ proj,
    const float* __restrict__ ctx, const float* __restrict__ ksum,
    u16* __restrict__ trans, int n)
{
  __shared__ float As[64][36];     // Q^T tile [d][node], 32 nodes
  __shared__ float Bc[64][68];     // proj^T chunk / ctx chunk
  __shared__ __half qp_s[32][274];
  __shared__ float diag[32];
  __shared__ float mxs[32];
  __shared__ float dinvs[32];
  const int tid = threadIdx.x;
  const int h = blockIdx.y;
  const int node0 = blockIdx.x*32;
  const int tx = tid&15, ty = tid>>4;
  {
    int nn = tid>>3, d0 = (tid&7)*8;
    uint4 raw = make_uint4(0,0,0,0);
    if (node0+nn < n) raw = *(const uint4*)(Q + (((size_t)h*n + node0+nn)<<6) + d0);
    const u16* p = (const u16*)&raw;
    #pragma unroll
    for (int s=0;s<8;s++) As[d0+s][nn] = bf2f(p[s]);
  }
  __syncthreads();
  if (tid < 32){
    float s = 0.f;
    #pragma unroll 8
    for (int d=0; d<64; ++d){ float v = As[d][tid]; s += v*v; }
    diag[tid] = 0.0625f*s;
  }
  #pragma unroll 1
  for (int mc=0; mc<5; ++mc){
    __syncthreads();
    #pragma unroll
    for (int q=0;q<4;q++){
      int fl = tid + q*256;
      int ml = fl>>4, dq = (fl&15)*4;
      int m = mc*64 + ml;
      float4 pv = make_float4(0.f,0.f,0.f,0.f);
      if (m < MF) pv = *(const float4*)(proj + (size_t)m*64 + dq);
      Bc[dq+0][ml]=pv.x; Bc[dq+1][ml]=pv.y; Bc[dq+2][ml]=pv.z; Bc[dq+3][ml]=pv.w;
    }
    __syncthreads();
    float acc[2][4] = {};
    #pragma unroll 4
    for (int d=0; d<64; ++d){
      float2 a2 = *(const float2*)&As[d][ty*2];
      float4 b4 = *(const float4*)&Bc[d][tx*4];
      acc[0][0]+=a2.x*b4.x; acc[0][1]+=a2.x*b4.y; acc[0][2]+=a2.x*b4.z; acc[0][3]+=a2.x*b4.w;
      acc[1][0]+=a2.y*b4.x; acc[1][1]+=a2.y*b4.y; acc[1][2]+=a2.y*b4.z; acc[1][3]+=a2.y*b4.w;
    }
    #pragma unroll
    for (int i=0;i<2;i++)
      #pragma unroll
      for (int j=0;j<4;j++){
        int m = mc*64 + tx*4 + j;
        if (m < MF) qp_s[ty*2+i][m] = __float2half(DN*acc[i][j]);
      }
  }
  __syncthreads();
  const int t8 = tid&7, n8 = tid>>3;
  {
    float mx = -3.0e38f;
    for (int m = t8; m < MF; m += 8) mx = fmaxf(mx, __half2float(qp_s[n8][m]));
    mx = fmaxf(mx, __shfl_xor(mx, 1, 8));
    mx = fmaxf(mx, __shfl_xor(mx, 2, 8));
    mx = fmaxf(mx, __shfl_xor(mx, 4, 8));
    if (t8==0) mxs[n8] = mx;
  }
  __syncthreads();
  for (int idx = tid; idx < 32*MF; idx += 256){
    int nn = idx / MF, m = idx - nn*MF;
    float v = __half2float(qp_s[nn][m]);
    qp_s[nn][m] = __float2half(RATIO*(expf(v - diag[nn] - mxs[nn]) + EPSRF));
  }
  __syncthreads();
  {
    float s = 0.f;
    for (int m = t8; m < MF; m += 8) s += __half2float(qp_s[n8][m]) * ksum[(size_t)h*MF + m];
    s += __shfl_xor(s, 1, 8); s += __shfl_xor(s, 2, 8); s += __shfl_xor(s, 4, 8);
    if (t8==0) dinvs[n8] = 1.f/s;
  }
  float acco[2][4] = {};
  #pragma unroll 1
  for (int mc=0; mc<5; ++mc){
    __syncthreads();
    #pragma unroll
    for (int q=0;q<4;q++){
      int fl = tid + q*256;
      int ml = fl>>4, dq = (fl&15)*4;
      int m = mc*64 + ml;
      float4 cv = make_float4(0.f,0.f,0.f,0.f);
      if (m < MF) cv = *(const float4*)(ctx + (((size_t)h*MF + m)<<6) + dq);
      *(float4*)&Bc[ml][dq] = cv;
    }
    __syncthreads();
    const int cmax = (mc<4)? 64 : (MF-256);
    #pragma unroll 4
    for (int ml=0; ml<cmax; ++ml){
      float a0 = __half2float(qp_s[ty*2+0][mc*64+ml]);
      float a1 = __half2float(qp_s[ty*2+1][mc*64+ml]);
      float4 b4 = *(const float4*)&Bc[ml][tx*4];
      acco[0][0]+=a0*b4.x; acco[0][1]+=a0*b4.y; acco[0][2]+=a0*b4.z; acco[0][3]+=a0*b4.w;
      acco[1][0]+=a1*b4.x; acco[1][1]+=a1*b4.y; acco[1][2]+=a1*b4.z; acco[1][3]+=a1*b4.w;
    }
  }
  #pragma unroll
  for (int i=0;i<2;i++){
    int ng = node0 + ty*2 + i;
    if (ng < n){
      float dv = dinvs[ty*2+i];
      ushort4 o;
      o.x = f2bf(acco[i][0]*dv); o.y = f2bf(acco[i][1]*dv);
      o.z = f2bf(acco[i][2]*dv); o.w = f2bf(acco[i][3]*dv);
      *(ushort4*)(trans + (size_t)ng*256 + h*64 + tx*4) = o;
    }
  }
}

// ---------------- small transpose for lin2_w ----------------
__global__ void k_tr_l2(const float* __restrict__ w, float* __restrict__ wT){
  int i = blockIdx.x*256 + threadIdx.x;
  if (i < 32*512){ int o = i>>9, f = i&511; wT[f*32 + o] = w[i]; }
}

// ---------------- K5: cat -> elu -> lin2 -> elu ----------------
__global__ __launch_bounds__(256) void k_gnn2(
    const u16* __restrict__ G1, const u16* __restrict__ trans,
    const float* __restrict__ l2wT, const float* __restrict__ l2b,
    float* __restrict__ out, int n)
{
  __shared__ u16 cat_s[32][516];
  const int tid = threadIdx.x;
  const int node0 = blockIdx.x*32;
  for (int e = tid; e < 32*512; e += 256){
    int nn = e>>9, f = e&511;
    int ng = node0+nn; float v = 0.f;
    if (ng<n) v = bf2f(f<256 ? G1[(size_t)ng*256+f] : trans[(size_t)ng*256+f-256]);
    cat_s[nn][f] = f2bf(eluf(v));
  }
  __syncthreads();
  const int o = tid&31, half = tid>>5;
  float bb = l2b[o];
  float acc[4] = {bb,bb,bb,bb};
  for (int f=0; f<512; ++f){
    float w = l2wT[f*32 + o];
    #pragma unroll
    for (int i=0;i<4;i++) acc[i] += bf2f(cat_s[half + i*8][f]) * w;
  }
  #pragma unroll
  for (int i=0;i<4;i++){
    int ng = node0 + half + i*8;
    if (ng<n) out[(size_t)ng*32 + o] = eluf(acc[i]);
  }
}

// ---------------- edge layout detect (int32 vs int64) ----------------
__global__ void k_edgemode(const int* __restrict__ ei, int* __restrict__ mode){
  __shared__ int any;
  if (threadIdx.x==0) any = 0;
  __syncthreads();
  if (ei[threadIdx.x*2+1] != 0) any = 1;
  __syncthreads();
  if (threadIdx.x==0) *mode = any;   // 1 = int32 layout, 0 = int64 layout
}
__device__ __forceinline__ int edge_at(const int* ei, int mode, size_t idx){
  if (mode) return ei[idx];
  return (int)((const long long*)ei)[idx];
}

// ---------------- CSR build ----------------
__global__ void k_hist(const int* __restrict__ ei, const int* __restrict__ mode,
                       u32* __restrict__ deg, int e){
  const int md = *mode;
  for (size_t i = (size_t)blockIdx.x*blockDim.x + threadIdx.x; i < (size_t)e; i += (size_t)gridDim.x*blockDim.x)
    atomicAdd(&deg[edge_at(ei, md, (size_t)e + i)], 1u);
}
__global__ void k_dis(const u32* __restrict__ deg, float* __restrict__ dis, int n){
  int i = blockIdx.x*256 + threadIdx.x;
  if (i<n) dis[i] = rsqrtf((float)(deg[i] + 1u));
}
__global__ __launch_bounds__(1024) void k_scan(const u32* __restrict__ deg, u32* __restrict__ rowp, int n){
  __shared__ u32 sm[1024];
  __shared__ u32 carry;
  if (threadIdx.x==0){ carry = 0u; rowp[0] = 0u; }
  __syncthreads();
  for (int base=0; base<n; base+=1024){
    int i = base + (int)threadIdx.x;
    u32 v = (i<n)? deg[i] : 0u;
    sm[threadIdx.x] = v; __syncthreads();
    for (int off=1; off<1024; off<<=1){
      u32 t = (threadIdx.x>=(u32)off)? sm[threadIdx.x-off] : 0u;
      __syncthreads();
      sm[threadIdx.x] += t;
      __syncthreads();
    }
    if (i<n) rowp[i+1] = carry + sm[threadIdx.x];
    __syncthreads();
    if (threadIdx.x==0) carry += sm[1023];
    __syncthreads();
  }
}
__global__ void k_copy(const u32* __restrict__ a, u32* __restrict__ b, int n){
  int i = blockIdx.x*256 + threadIdx.x; if (i<n) b[i]=a[i];
}
__global__ void k_fill(const int* __restrict__ ei, const int* __restrict__ mode,
                       const float* __restrict__ dis,
                       u32* __restrict__ cur, int* __restrict__ col, float* __restrict__ wgt, int e){
  const int md = *mode;
  for (size_t i = (size_t)blockIdx.x*blockDim.x + threadIdx.x; i < (size_t)e; i += (size_t)gridDim.x*blockDim.x){
    int s = edge_at(ei, md, i);
    int t = edge_at(ei, md, (size_t)e + i);
    u32 pos = atomicAdd(&cur[t], 1u);
    col[pos] = s;
    wgt[pos] = dis[s]*dis[t];
  }
}

// ---------------- APPNP iteration (gather form) ----------------
__global__ __launch_bounds__(256) void k_appnp(
    const float* __restrict__ xin, const float* __restrict__ hbuf,
    float* __restrict__ xout, const u32* __restrict__ rowp,
    const int* __restrict__ col, const float* __restrict__ wgt,
    const float* __restrict__ dis, int n)
{
  const int g = threadIdx.x>>5, j = threadIdx.x&31;
  const int node = blockIdx.x*8 + g;
  if (node >= n) return;
  float d0 = dis[node];
  float acc = d0*d0*xin[((size_t)node<<5) + j];
  u32 r0 = rowp[node], r1 = rowp[node+1];
  for (u32 k = r0; k < r1; ++k)
    acc += wgt[k] * xin[((size_t)col[k]<<5) + j];
  xout[((size_t)node<<5)+j] = 0.9f*acc + 0.1f*hbuf[((size_t)node<<5)+j];
}

// ---------------- log_softmax + raw ----------------
__global__ __launch_bounds__(256) void k_lsm(const float* __restrict__ xin, float* __restrict__ out, int n){
  const int g = threadIdx.x>>5, j = threadIdx.x&31;
  const int node = blockIdx.x*8 + g;
  if (node>=n) return;
  float v = xin[((size_t)node<<5)+j];
  float m = v;
  #pragma unroll
  for (int o=16;o;o>>=1) m = fmaxf(m, __shfl_xor(m, o, 32));
  float s = expf(v - m);
  #pragma unroll
  for (int o=16;o;o>>=1) s += __shfl_xor(s, o, 32);
  out[((size_t)node<<5)+j] = v - m - logf(s);
  out[(size_t)n*32 + ((size_t)node<<5)+j] = v;
}

extern "C" void kernel_launch(void* const* d_in, const int* in_sizes, int n_in,
                              void* d_out, int out_size, void* d_ws, size_t ws_size,
                              hipStream_t stream)
{
  const float* x   = (const float*)d_in[0];
  const int*   ei  = (const int*)  d_in[1];
  const float* l1w = (const float*)d_in[2];
  const float* l1b = (const float*)d_in[3];
  const float* l2w = (const float*)d_in[4];
  const float* l2b = (const float*)d_in[5];
  const float* qw  = (const float*)d_in[6];
  const float* qb  = (const float*)d_in[7];
  const float* kw  = (const float*)d_in[8];
  const float* kb  = (const float*)d_in[9];
  const float* vw  = (const float*)d_in[10];
  const float* vb  = (const float*)d_in[11];
  const float* proj= (const float*)d_in[12];
  const int n = in_sizes[0] / 256;
  const int e = in_sizes[1] / 2;

  char* ws = (char*)d_ws;
  auto au = [](size_t v){ return (v + 255) & ~(size_t)255; };
  const size_t bQ = (size_t)n * 512;                 // bf16 [4][n][64]
  const size_t oQ = 0;
  const size_t oK = au(oQ + bQ);
  const size_t oV = au(oK + bQ);
  const size_t oG1 = au(oV + bQ);
  const size_t oCtxp = au(oG1 + bQ);
  const size_t bCtxp = (size_t)NH*NBCTX*MF*64*4;
  const size_t oKsump = au(oCtxp + bCtxp);
  const size_t bKsump = (size_t)NH*NBCTX*MF*4;
  const size_t oCtx = au(oKsump + bKsump);
  const size_t oKsum = au(oCtx + (size_t)NH*MF*64*4);
  const size_t oKmax = au(oKsum + (size_t)NH*MF*4);
  const size_t oMode = oKmax + 64;
  const size_t oL2wT = au(oKmax + 256);
  // aliases (Q region dead after k_qattn; K region dead after k_ctx; V dead after k_ctx)
  const size_t oTrans = oK;
  const size_t oG2 = oQ;
  const size_t oXA = au(oG2 + (size_t)n*32*4);
  const size_t oXB = au(oXA + (size_t)n*32*4);
  const size_t oDeg = au(oXB + (size_t)n*32*4);
  const size_t oDis = au(oDeg + (size_t)n*4);
  const size_t oRowp= au(oDis + (size_t)n*4);
  const size_t oCur = au(oRowp + (size_t)(n+1)*4);
  const size_t oCol = oV;
  const size_t oWgt = au(oCol + (size_t)e*4);
  (void)oCur; (void)oWgt; (void)ws_size; (void)n_in; (void)out_size;

  u16* Q  = (u16*)(ws + oQ);
  u16* Kb = (u16*)(ws + oK);
  u16* Vb = (u16*)(ws + oV);
  u16* G1 = (u16*)(ws + oG1);
  float* ctxp = (float*)(ws + oCtxp);
  float* ksump= (float*)(ws + oKsump);
  float* ctx  = (float*)(ws + oCtx);
  float* ksum = (float*)(ws + oKsum);
  u32*  kmax  = (u32*)(ws + oKmax);
  int*  mode  = (int*)(ws + oMode);
  float* l2wT = (float*)(ws + oL2wT);
  u16* trans  = (u16*)(ws + oTrans);
  float* G2   = (float*)(ws + oG2);
  float* xA   = (float*)(ws + oXA);
  float* xB   = (float*)(ws + oXB);
  u32* deg    = (u32*)(ws + oDeg);
  float* dis  = (float*)(ws + oDis);
  u32* rowp   = (u32*)(ws + oRowp);
  u32* cur    = (u32*)(ws + oCur);
  int* col    = (int*)(ws + oCol);
  float* wgt  = (float*)(ws + oWgt);

  const int nt64 = (n+63)/64, nt32 = (n+31)/32;

  hipMemsetAsync(ws + oKmax, 0, 16, stream);
  k_proj<<<dim3(nt64,16),256,0,stream>>>(x,qw,kw,vw,l1w,qb,kb,vb,l1b,Q,Kb,Vb,G1,n);
  k_kmax<<<dim3(nt64,4),256,0,stream>>>(Kb,proj,kmax,n);
  k_ctx<<<dim3(NBCTX,20),256,0,stream>>>(Kb,Vb,proj,kmax,ctxp,ksump,n);
  {
    int tot = NH*MF*64 + NH*MF;
    k_reduce<<<(tot+255)/256,256,0,stream>>>(ctxp,ksump,ctx,ksum);
  }
  k_qattn<<<dim3(nt32,4),256,0,stream>>>(Q,proj,ctx,ksum,trans,n);
  k_tr_l2<<<64,256,0,stream>>>(l2w,l2wT);
  k_gnn2<<<nt32,256,0,stream>>>(G1,trans,l2wT,l2b,G2,n);
  // ---- APPNP ----
  k_edgemode<<<1,256,0,stream>>>(ei,mode);
  hipMemsetAsync(ws + oDeg, 0, (size_t)n*4, stream);
  k_hist<<<2048,256,0,stream>>>(ei,mode,deg,e);
  k_dis<<<(n+255)/256,256,0,stream>>>(deg,dis,n);
  k_scan<<<1,1024,0,stream>>>(deg,rowp,n);
  k_copy<<<(n+255)/256,256,0,stream>>>(rowp,cur,n);
  k_fill<<<2048,256,0,stream>>>(ei,mode,dis,cur,col,wgt,e);
  const float* curx = G2;
  float* bufs[2] = {xA, xB};
  for (int it=0; it<10; ++it){
    float* nxt = bufs[it&1];
    k_appnp<<<(n+7)/8,256,0,stream>>>(curx,G2,nxt,rowp,col,wgt,dis,n);
    curx = nxt;
  }
  k_lsm<<<(n+7)/8,256,0,stream>>>(curx,(float*)d_out,n);
}

// Round 3
// 3228.572 us; speedup vs baseline: 1.5161x; 1.5161x over previous
//
#include <hip/hip_runtime.h>
#include <hip/hip_fp16.h>

#define NH 4
#define HD 64
#define MF 266
#define MP 288           // MF padded to multiple of 32 for MFMA K-steps
#define NB 96            // k_ctx partial blocks
#define DN 0.35355339059327373f
#define RATIO 0.06131393394849658f
#define EPSRF 1e-4f
#define REPS (RATIO*EPSRF)

typedef unsigned short u16;
typedef unsigned int u32;
typedef __attribute__((ext_vector_type(8))) short bf16x8;
typedef __attribute__((ext_vector_type(4))) float f32x4;
#define MFMA16(a,b,c) __builtin_amdgcn_mfma_f32_16x16x32_bf16(a,b,c,0,0,0)

__device__ __forceinline__ float bf2f(u16 u){ return __uint_as_float(((u32)u)<<16); }
__device__ __forceinline__ u16 f2bf(float f){ u32 u = __float_as_uint(f); u += 0x7FFFu + ((u>>16)&1u); return (u16)(u>>16); }
__device__ __forceinline__ float eluf(float x){ return x>0.f ? x : (expf(x)-1.f); }

// ---------------- weight/proj conversion to bf16 ----------------
__global__ void k_cvtw(const float* __restrict__ qw, const float* __restrict__ kw,
                       const float* __restrict__ vw, const float* __restrict__ lw,
                       const float* __restrict__ proj,
                       u16* __restrict__ Wb, u16* __restrict__ projp){
  int i = blockIdx.x*256 + threadIdx.x;
  if (i < 262144){
    int sec = i>>16, r = i&65535;
    const float* s = sec==0?qw : sec==1?kw : sec==2?vw : lw;
    Wb[i] = f2bf(s[r]);
  }
  if (i < MP*64){
    int r = i>>6, c = i&63;
    projp[i] = f2bf(r < MF ? proj[r*64 + c] : 0.f);
  }
}

// ---------------- K1: fused projection GEMM (MFMA) ----------------
// C[n x 1024] = X @ W^T. Block 128x128 (4 waves, each 64x64).
__global__ __launch_bounds__(256) void k_proj(
    const float* __restrict__ x, const u16* __restrict__ Wb,
    const float* __restrict__ qb, const float* __restrict__ kb,
    const float* __restrict__ vb, const float* __restrict__ lb,
    u16* __restrict__ Q, u16* __restrict__ K, u16* __restrict__ V,
    u16* __restrict__ G1, int n)
{
  const int tid = threadIdx.x;
  const int w = tid>>6, l = tid&63;
  const int wr = w>>1, wc = w&1;
  const int r0 = blockIdx.x*128 + wr*64;
  const int c0 = blockIdx.y*128 + wc*64;
  const int lm = l&15, lk = l>>4;
  f32x4 acc[4][4] = {};
  #pragma unroll 1
  for (int kt=0; kt<8; ++kt){
    const int k0 = kt*32;
    bf16x8 Af[4], Bf[4];
    #pragma unroll
    for (int i=0;i<4;i++){
      int rr = r0 + i*16 + lm; if (rr > n-1) rr = n-1;
      const float* xp = x + (size_t)rr*256 + k0 + lk*8;
      float4 a0 = *(const float4*)xp;
      float4 a1 = *(const float4*)(xp+4);
      union { u32 u[4]; bf16x8 v; } cv;
      cv.u[0] = ((u32)f2bf(a0.y)<<16) | f2bf(a0.x);
      cv.u[1] = ((u32)f2bf(a0.w)<<16) | f2bf(a0.z);
      cv.u[2] = ((u32)f2bf(a1.y)<<16) | f2bf(a1.x);
      cv.u[3] = ((u32)f2bf(a1.w)<<16) | f2bf(a1.z);
      Af[i] = cv.v;
      Bf[i] = *(const bf16x8*)(Wb + (size_t)(c0 + i*16 + lm)*256 + k0 + lk*8);
    }
    #pragma unroll
    for (int i=0;i<4;i++)
      #pragma unroll
      for (int j=0;j<4;j++)
        acc[i][j] = MFMA16(Af[i], Bf[j], acc[i][j]);
  }
  const int sel = c0>>8;
  const float* bp = sel==0?qb : sel==1?kb : sel==2?vb : lb;
  #pragma unroll
  for (int j=0;j<4;j++){
    const int c = c0 + j*16 + lm;
    const int cc = c&255;
    const float bias = bp[cc];
    #pragma unroll
    for (int i=0;i<4;i++){
      #pragma unroll
      for (int jr=0;jr<4;jr++){
        const int r = r0 + i*16 + lk*4 + jr;
        if (r < n){
          u16 bv = f2bf(acc[i][j][jr] + bias);
          if (sel==3) G1[(size_t)r*256 + cc] = bv;
          else {
            u16* d3 = sel==0?Q : sel==1?K : V;
            d3[(((size_t)(cc>>6)*n + r)<<6) + (cc&63)] = bv;
          }
        }
      }
    }
  }
}

// ---------------- V column sums (for EPS correction) ----------------
__global__ void k_vcs(const u16* __restrict__ Vb, float* __restrict__ vcs, int n){
  const int h = blockIdx.y, tid = threadIdx.x;
  const int d = tid&63, seg = tid>>6;
  float s = 0.f;
  for (int node = blockIdx.x*4 + seg; node < n; node += 256)
    s += bf2f(Vb[(((size_t)h*n + node)<<6) + d]);
  __shared__ float sm[4][64];
  sm[seg][d] = s; __syncthreads();
  if (tid < 64){
    float t2 = sm[0][tid]+sm[1][tid]+sm[2][tid]+sm[3][tid];
    atomicAdd(vcs + h*64 + tid, t2);
  }
}

// ---------------- K3: unshifted kp -> ksum0/ctx0 partials + global dash max ----------------
__global__ __launch_bounds__(256) void k_ctx(
    const u16* __restrict__ Kb, const u16* __restrict__ Vb,
    const u16* __restrict__ projp,
    float* __restrict__ ctxp, float* __restrict__ ksump,
    u32* __restrict__ kmaxg, int n)
{
  __shared__ u16 Vt[64][72];      // V^T tile [d][node]
  __shared__ u16 kp_lds[32][72];  // kp^T [m-local][node]
  __shared__ float redk[4][2][16];
  __shared__ float redm[4];
  const int tid = threadIdx.x;
  const int w = tid>>6, l = tid&63;
  const int bb = blockIdx.x;
  const int h = blockIdx.y/9, mc = blockIdx.y%9;
  const int lm = l&15, lk = l>>4;
  bf16x8 bfr[2][2];
  #pragma unroll
  for (int mt=0;mt<2;++mt)
    #pragma unroll
    for (int ks=0;ks<2;++ks)
      bfr[mt][ks] = *(const bf16x8*)(projp + (size_t)(mc*32 + mt*16 + lm)*64 + ks*32 + lk*8);
  f32x4 cacc0 = {0,0,0,0}, cacc1 = {0,0,0,0};
  float ksa0 = 0.f, ksa1 = 0.f;
  float mreg = -3.0e38f;
  const int ntile = (n+63)>>6;
  #pragma unroll 1
  for (int t=bb; t<ntile; t+=NB){
    const int n0 = t*64;
    __syncthreads();
    #pragma unroll
    for (int q=0;q<2;q++){
      int e8 = tid + q*256;
      int nn = e8>>3, d0 = (e8&7)*8;
      uint4 rv = make_uint4(0,0,0,0);
      if (n0+nn < n) rv = *(const uint4*)(Vb + (((size_t)h*n + n0+nn)<<6) + d0);
      const u16* pv = (const u16*)&rv;
      #pragma unroll
      for (int s=0;s<8;s++) Vt[d0+s][nn] = pv[s];
    }
    const u16* Kbase = Kb + (((size_t)h*n + n0 + w*16 + lm)<<6);
    bf16x8 af0 = *(const bf16x8*)(Kbase + lk*8);
    bf16x8 af1 = *(const bf16x8*)(Kbase + 32 + lk*8);
    float dg = 0.f;
    #pragma unroll
    for (int i2=0;i2<8;i2++){
      float a = bf2f(((const u16*)&af0)[i2]);
      float b = bf2f(((const u16*)&af1)[i2]);
      dg += a*a + b*b;
    }
    dg += __shfl_xor(dg,16); dg += __shfl_xor(dg,32);
    dg *= 0.0625f;
    float dgr[4];
    #pragma unroll
    for (int j=0;j<4;j++) dgr[j] = __shfl(dg, lk*4+j, 16);
    f32x4 D0 = {0,0,0,0}, D1 = {0,0,0,0};
    D0 = MFMA16(af0, bfr[0][0], D0);
    D0 = MFMA16(af1, bfr[0][1], D0);
    D1 = MFMA16(af0, bfr[1][0], D1);
    D1 = MFMA16(af1, bfr[1][1], D1);
    #pragma unroll
    for (int mt=0; mt<2; ++mt){
      const f32x4 Dm = mt ? D1 : D0;
      const int m = mc*32 + mt*16 + lm;
      const bool vm = m < MF;
      float colsum = 0.f;
      u32 pk0 = 0, pk1 = 0;
      #pragma unroll
      for (int j=0;j<4;j++){
        float ddash = DN * Dm[j];
        float kp = 0.f;
        if (vm && (n0 + w*16 + lk*4 + j) < n){
          kp = RATIO * __expf(ddash - dgr[j]);
          mreg = fmaxf(mreg, ddash);
          colsum += kp;
        }
        if (j<2) pk0 |= ((u32)f2bf(kp)) << (16*j);
        else     pk1 |= ((u32)f2bf(kp)) << (16*(j-2));
      }
      *(u32*)&kp_lds[mt*16+lm][w*16 + lk*4]     = pk0;
      *(u32*)&kp_lds[mt*16+lm][w*16 + lk*4 + 2] = pk1;
      colsum += __shfl_xor(colsum,16); colsum += __shfl_xor(colsum,32);
      if (mt==0) ksa0 += colsum; else ksa1 += colsum;
    }
    __syncthreads();
    #pragma unroll
    for (int ks=0;ks<2;++ks){
      bf16x8 bv = *(const bf16x8*)&Vt[w*16+lm][ks*32 + lk*8];
      bf16x8 a0 = *(const bf16x8*)&kp_lds[lm][ks*32 + lk*8];
      bf16x8 a1 = *(const bf16x8*)&kp_lds[16+lm][ks*32 + lk*8];
      cacc0 = MFMA16(a0, bv, cacc0);
      cacc1 = MFMA16(a1, bv, cacc1);
    }
  }
  float* cp = ctxp + ((size_t)(h*NB + bb))*MP*64;
  #pragma unroll
  for (int mt=0;mt<2;++mt){
    const f32x4 cc2 = mt ? cacc1 : cacc0;
    #pragma unroll
    for (int j=0;j<4;j++){
      int m = mc*32 + mt*16 + lk*4 + j;
      cp[(size_t)m*64 + w*16 + lm] = cc2[j];
    }
  }
  if (l < 16){ redk[w][0][l] = ksa0; redk[w][1][l] = ksa1; }
  float mr = mreg;
  #pragma unroll
  for (int s=1;s<64;s<<=1) mr = fmaxf(mr, __shfl_xor(mr, s));
  if (l==0) redm[w] = mr;
  __syncthreads();
  if (tid < 32){
    int mt = tid>>4, mm = tid&15;
    float s = redk[0][mt][mm]+redk[1][mt][mm]+redk[2][mt][mm]+redk[3][mt][mm];
    ksump[((size_t)(h*NB+bb))*MP + mc*32 + mt*16 + mm] = s;
  }
  if (tid==0){
    float bm = fmaxf(fmaxf(redm[0],redm[1]), fmaxf(redm[2],redm[3]));
    u32 b = __float_as_uint(bm);
    u32 enc = (b & 0x80000000u) ? ~b : (b | 0x80000000u);
    atomicMax(kmaxg + h, enc);
  }
}

// ---------------- K3b: reduce partials + apply max/EPS correction ----------------
__global__ void k_reduce(const float* __restrict__ ctxp, const float* __restrict__ ksump,
                         const u32* __restrict__ kmaxg, const float* __restrict__ vcs,
                         u16* __restrict__ ctxT, float* __restrict__ ksum, int n)
{
  const int T1 = NH*MP*64;
  int idx = blockIdx.x*256 + threadIdx.x;
  if (idx < T1){
    int h = idx/(MP*64), r = idx - h*MP*64, m = r>>6, d = r&63;
    u32 ee = kmaxg[h]; u32 b = (ee & 0x80000000u) ? (ee ^ 0x80000000u) : ~ee;
    float sc = __expf(-__uint_as_float(b));
    float s = 0.f;
    for (int bb=0; bb<NB; ++bb) s += ctxp[(((size_t)(h*NB+bb))*MP + m)*64 + d];
    float val = (m < MF) ? (sc*s + REPS*vcs[h*64 + d]) : 0.f;
    ctxT[((size_t)h*64 + d)*MP + m] = f2bf(val);
  } else if (idx < T1 + NH*MP){
    int k2 = idx - T1, h = k2/MP, m = k2 - h*MP;
    u32 ee = kmaxg[h]; u32 b = (ee & 0x80000000u) ? (ee ^ 0x80000000u) : ~ee;
    float sc = __expf(-__uint_as_float(b));
    float s = 0.f;
    for (int bb=0; bb<NB; ++bb) s += ksump[((size_t)(h*NB+bb))*MP + m];
    ksum[h*MP + m] = (m < MF) ? (sc*s + REPS*(float)n) : 0.f;
  }
}

// ---------------- K4: query path (MFMA) ----------------
__global__ __launch_bounds__(256) void k_qattn(
    const u16* __restrict__ Qb, const u16* __restrict__ projp,
    const u16* __restrict__ ctxT, const float* __restrict__ ksum,
    u16* __restrict__ trans, int n)
{
  __shared__ u16 qp_lds[4][16][296];
  const int tid = threadIdx.x;
  const int w = tid>>6, l = tid&63;
  const int h = blockIdx.y;
  const int nb = blockIdx.x*64 + w*16;
  const int lm = l&15, lk = l>>4;
  int rr = nb + lm; if (rr > n-1) rr = n-1;
  const u16* Qbase = Qb + (((size_t)h*n + rr)<<6);
  bf16x8 af0 = *(const bf16x8*)(Qbase + lk*8);
  bf16x8 af1 = *(const bf16x8*)(Qbase + 32 + lk*8);
  float dg = 0.f;
  #pragma unroll
  for (int i2=0;i2<8;i2++){
    float a = bf2f(((const u16*)&af0)[i2]);
    float b = bf2f(((const u16*)&af1)[i2]);
    dg += a*a + b*b;
  }
  dg += __shfl_xor(dg,16); dg += __shfl_xor(dg,32);
  dg *= 0.0625f;
  float dgr[4];
  #pragma unroll
  for (int j=0;j<4;j++) dgr[j] = __shfl(dg, lk*4+j, 16);
  f32x4 D[17];
  #pragma unroll
  for (int mt=0;mt<17;++mt){
    bf16x8 b0 = *(const bf16x8*)(projp + (size_t)(mt*16+lm)*64 + lk*8);
    bf16x8 b1 = *(const bf16x8*)(projp + (size_t)(mt*16+lm)*64 + 32 + lk*8);
    f32x4 z = {0,0,0,0};
    z = MFMA16(af0, b0, z);
    z = MFMA16(af1, b1, z);
    D[mt] = z;
  }
  float rmax[4] = {-3.0e38f,-3.0e38f,-3.0e38f,-3.0e38f};
  #pragma unroll
  for (int mt=0;mt<17;++mt){
    const bool vm = (mt<16) || (lm<10);
    #pragma unroll
    for (int j=0;j<4;j++){
      float dd = DN*D[mt][j];
      if (vm) rmax[j] = fmaxf(rmax[j], dd);
    }
  }
  #pragma unroll
  for (int j=0;j<4;j++){
    #pragma unroll
    for (int s=1;s<16;s<<=1) rmax[j] = fmaxf(rmax[j], __shfl_xor(rmax[j], s));
  }
  float den[4] = {0,0,0,0};
  #pragma unroll
  for (int mt=0;mt<17;++mt){
    const int m = mt*16 + lm;
    const float ksm = ksum[h*MP + m];
    #pragma unroll
    for (int j=0;j<4;j++){
      float qp = RATIO*(__expf(DN*D[mt][j] - dgr[j] - rmax[j]) + EPSRF);
      den[j] += qp * ksm;
      qp_lds[w][lk*4+j][m] = f2bf(qp);
    }
  }
  #pragma unroll
  for (int j=0;j<4;j++) qp_lds[w][lk*4+j][272+lm] = 0;
  #pragma unroll
  for (int j=0;j<4;j++){
    #pragma unroll
    for (int s=1;s<16;s<<=1) den[j] += __shfl_xor(den[j], s);
  }
  __syncthreads();
  f32x4 o[4] = {{0,0,0,0},{0,0,0,0},{0,0,0,0},{0,0,0,0}};
  #pragma unroll
  for (int ks=0;ks<9;++ks){
    bf16x8 av = *(const bf16x8*)&qp_lds[w][lm][ks*32 + lk*8];
    #pragma unroll
    for (int dt=0;dt<4;++dt){
      bf16x8 bv = *(const bf16x8*)(ctxT + (size_t)(h*64 + dt*16 + lm)*MP + ks*32 + lk*8);
      o[dt] = MFMA16(av, bv, o[dt]);
    }
  }
  #pragma unroll
  for (int j=0;j<4;j++){
    const int node = nb + lk*4 + j;
    if (node < n){
      const float dv = 1.f/den[j];
      #pragma unroll
      for (int dt=0;dt<4;++dt)
        trans[(size_t)node*256 + h*64 + dt*16 + lm] = f2bf(o[dt][j]*dv);
    }
  }
}

// ---------------- small transpose for lin2_w ----------------
__global__ void k_tr_l2(const float* __restrict__ w, float* __restrict__ wT){
  int i = blockIdx.x*256 + threadIdx.x;
  if (i < 32*512){ int o = i>>9, f = i&511; wT[f*32 + o] = w[i]; }
}

// ---------------- K5: cat -> elu -> lin2 -> elu ----------------
__global__ __launch_bounds__(256) void k_gnn2(
    const u16* __restrict__ G1, const u16* __restrict__ trans,
    const float* __restrict__ l2wT, const float* __restrict__ l2b,
    float* __restrict__ out, int n)
{
  __shared__ u16 cat_s[32][516];
  const int tid = threadIdx.x;
  const int node0 = blockIdx.x*32;
  for (int e = tid; e < 32*512; e += 256){
    int nn = e>>9, f = e&511;
    int ng = node0+nn; float v = 0.f;
    if (ng<n) v = bf2f(f<256 ? G1[(size_t)ng*256+f] : trans[(size_t)ng*256+f-256]);
    cat_s[nn][f] = f2bf(eluf(v));
  }
  __syncthreads();
  const int o = tid&31, half = tid>>5;
  float bb = l2b[o];
  float acc[4] = {bb,bb,bb,bb};
  for (int f=0; f<512; ++f){
    float w = l2wT[f*32 + o];
    #pragma unroll
    for (int i=0;i<4;i++) acc[i] += bf2f(cat_s[half + i*8][f]) * w;
  }
  #pragma unroll
  for (int i=0;i<4;i++){
    int ng = node0 + half + i*8;
    if (ng<n) out[(size_t)ng*32 + o] = eluf(acc[i]);
  }
}

// ---------------- edge layout detect ----------------
__global__ void k_edgemode(const int* __restrict__ ei, int* __restrict__ mode){
  __shared__ int any;
  if (threadIdx.x==0) any = 0;
  __syncthreads();
  if (ei[threadIdx.x*2+1] != 0) any = 1;
  __syncthreads();
  if (threadIdx.x==0) *mode = any;
}
__device__ __forceinline__ int edge_at(const int* ei, int mode, size_t idx){
  if (mode) return ei[idx];
  return (int)((const long long*)ei)[idx];
}

// ---------------- CSR build ----------------
__global__ void k_hist(const int* __restrict__ ei, const int* __restrict__ mode,
                       u32* __restrict__ deg, int e){
  const int md = *mode;
  for (size_t i = (size_t)blockIdx.x*blockDim.x + threadIdx.x; i < (size_t)e; i += (size_t)gridDim.x*blockDim.x)
    atomicAdd(&deg[edge_at(ei, md, (size_t)e + i)], 1u);
}
__global__ void k_dis(const u32* __restrict__ deg, float* __restrict__ dis, int n){
  int i = blockIdx.x*256 + threadIdx.x;
  if (i<n) dis[i] = rsqrtf((float)(deg[i] + 1u));
}
__global__ __launch_bounds__(1024) void k_scan(const u32* __restrict__ deg, u32* __restrict__ rowp, int n){
  __shared__ u32 sm[1024];
  __shared__ u32 carry;
  if (threadIdx.x==0){ carry = 0u; rowp[0] = 0u; }
  __syncthreads();
  for (int base=0; base<n; base+=1024){
    int i = base + (int)threadIdx.x;
    u32 v = (i<n)? deg[i] : 0u;
    sm[threadIdx.x] = v; __syncthreads();
    for (int off=1; off<1024; off<<=1){
      u32 t = (threadIdx.x>=(u32)off)? sm[threadIdx.x-off] : 0u;
      __syncthreads();
      sm[threadIdx.x] += t;
      __syncthreads();
    }
    if (i<n) rowp[i+1] = carry + sm[threadIdx.x];
    __syncthreads();
    if (threadIdx.x==0) carry += sm[1023];
    __syncthreads();
  }
}
__global__ void k_copy(const u32* __restrict__ a, u32* __restrict__ b, int n){
  int i = blockIdx.x*256 + threadIdx.x; if (i<n) b[i]=a[i];
}
__global__ void k_fill(const int* __restrict__ ei, const int* __restrict__ mode,
                       const float* __restrict__ dis,
                       u32* __restrict__ cur, int* __restrict__ col, float* __restrict__ wgt, int e){
  const int md = *mode;
  for (size_t i = (size_t)blockIdx.x*blockDim.x + threadIdx.x; i < (size_t)e; i += (size_t)gridDim.x*blockDim.x){
    int s = edge_at(ei, md, i);
    int t = edge_at(ei, md, (size_t)e + i);
    u32 pos = atomicAdd(&cur[t], 1u);
    col[pos] = s;
    wgt[pos] = dis[s]*dis[t];
  }
}

// ---------------- APPNP iteration ----------------
__global__ __launch_bounds__(256) void k_appnp(
    const float* __restrict__ xin, const float* __restrict__ hbuf,
    float* __restrict__ xout, const u32* __restrict__ rowp,
    const int* __restrict__ col, const float* __restrict__ wgt,
    const float* __restrict__ dis, int n)
{
  const int g = threadIdx.x>>5, j = threadIdx.x&31;
  const int node = blockIdx.x*8 + g;
  if (node >= n) return;
  float d0 = dis[node];
  float acc = d0*d0*xin[((size_t)node<<5) + j];
  u32 r0 = rowp[node], r1 = rowp[node+1];
  for (u32 k = r0; k < r1; ++k)
    acc += wgt[k] * xin[((size_t)col[k]<<5) + j];
  xout[((size_t)node<<5)+j] = 0.9f*acc + 0.1f*hbuf[((size_t)node<<5)+j];
}

// ---------------- log_softmax + raw ----------------
__global__ __launch_bounds__(256) void k_lsm(const float* __restrict__ xin, float* __restrict__ out, int n){
  const int g = threadIdx.x>>5, j = threadIdx.x&31;
  const int node = blockIdx.x*8 + g;
  if (node>=n) return;
  float v = xin[((size_t)node<<5)+j];
  float m = v;
  #pragma unroll
  for (int o=16;o;o>>=1) m = fmaxf(m, __shfl_xor(m, o, 32));
  float s = expf(v - m);
  #pragma unroll
  for (int o=16;o;o>>=1) s += __shfl_xor(s, o, 32);
  out[((size_t)node<<5)+j] = v - m - logf(s);
  out[(size_t)n*32 + ((size_t)node<<5)+j] = v;
}

extern "C" void kernel_launch(void* const* d_in, const int* in_sizes, int n_in,
                              void* d_out, int out_size, void* d_ws, size_t ws_size,
                              hipStream_t stream)
{
  const float* x   = (const float*)d_in[0];
  const int*   ei  = (const int*)  d_in[1];
  const float* l1w = (const float*)d_in[2];
  const float* l1b = (const float*)d_in[3];
  const float* l2w = (const float*)d_in[4];
  const float* l2b = (const float*)d_in[5];
  const float* qw  = (const float*)d_in[6];
  const float* qb  = (const float*)d_in[7];
  const float* kw  = (const float*)d_in[8];
  const float* kb  = (const float*)d_in[9];
  const float* vw  = (const float*)d_in[10];
  const float* vb  = (const float*)d_in[11];
  const float* proj= (const float*)d_in[12];
  const int n = in_sizes[0] / 256;
  const int e = in_sizes[1] / 2;

  char* ws = (char*)d_ws;
  auto au = [](size_t v){ return (v + 255) & ~(size_t)255; };
  const size_t bQ = (size_t)n * 512;
  const size_t oQ = 0;
  const size_t oK = au(oQ + bQ);
  const size_t oV = au(oK + bQ);
  const size_t oG1 = au(oV + bQ);
  const size_t oCtxp = au(oG1 + bQ);
  const size_t bCtxp = (size_t)NH*NB*MP*64*4;
  const size_t oKsump = au(oCtxp + bCtxp);
  const size_t bKsump = (size_t)NH*NB*MP*4;
  const size_t oCtxT = au(oKsump + bKsump);
  const size_t oKsum = au(oCtxT + (size_t)NH*64*MP*2);
  const size_t oKmax = au(oKsum + (size_t)NH*MP*4);
  const size_t oVcs  = oKmax + 256;
  const size_t oMode = oVcs + 1024;
  const size_t oL2wT = au(oMode + 256);
  const size_t oWb   = au(oL2wT + 65536);
  const size_t oProjp= au(oWb + (size_t)1024*256*2);
  const size_t oTrans = oK;
  const size_t oG2 = oQ;
  const size_t oXA = au(oG2 + (size_t)n*32*4);
  const size_t oXB = au(oXA + (size_t)n*32*4);
  const size_t oDeg = au(oXB + (size_t)n*32*4);
  const size_t oDis = au(oDeg + (size_t)n*4);
  const size_t oRowp= au(oDis + (size_t)n*4);
  const size_t oCur = au(oRowp + (size_t)(n+1)*4);
  const size_t oCol = oV;
  const size_t oWgt = au(oCol + (size_t)e*4);
  (void)ws_size; (void)n_in; (void)out_size;

  u16* Q  = (u16*)(ws + oQ);
  u16* Kb = (u16*)(ws + oK);
  u16* Vb = (u16*)(ws + oV);
  u16* G1 = (u16*)(ws + oG1);
  float* ctxp = (float*)(ws + oCtxp);
  float* ksump= (float*)(ws + oKsump);
  u16*  ctxT  = (u16*)(ws + oCtxT);
  float* ksum = (float*)(ws + oKsum);
  u32*  kmax  = (u32*)(ws + oKmax);
  float* Vcs  = (float*)(ws + oVcs);
  int*  mode  = (int*)(ws + oMode);
  float* l2wT = (float*)(ws + oL2wT);
  u16*  Wb    = (u16*)(ws + oWb);
  u16*  projp = (u16*)(ws + oProjp);
  u16* trans  = (u16*)(ws + oTrans);
  float* G2   = (float*)(ws + oG2);
  float* xA   = (float*)(ws + oXA);
  float* xB   = (float*)(ws + oXB);
  u32* deg    = (u32*)(ws + oDeg);
  float* dis  = (float*)(ws + oDis);
  u32* rowp   = (u32*)(ws + oRowp);
  u32* cur    = (u32*)(ws + oCur);
  int* col    = (int*)(ws + oCol);
  float* wgt  = (float*)(ws + oWgt);

  const int nt32 = (n+31)/32;

  k_cvtw<<<1024,256,0,stream>>>(qw,kw,vw,l1w,proj,Wb,projp);
  k_proj<<<dim3((n+127)/128,8),256,0,stream>>>(x,Wb,qb,kb,vb,l1b,Q,Kb,Vb,G1,n);
  hipMemsetAsync(ws + oKmax, 0, 16, stream);
  hipMemsetAsync(ws + oVcs, 0, 1024, stream);
  k_vcs<<<dim3(64,4),256,0,stream>>>(Vb,Vcs,n);
  k_ctx<<<dim3(NB,36),256,0,stream>>>(Kb,Vb,projp,ctxp,ksump,kmax,n);
  {
    int tot = NH*MP*64 + NH*MP;
    k_reduce<<<(tot+255)/256,256,0,stream>>>(ctxp,ksump,kmax,Vcs,ctxT,ksum,n);
  }
  k_qattn<<<dim3((n+63)/64,4),256,0,stream>>>(Q,projp,ctxT,ksum,trans,n);
  k_tr_l2<<<64,256,0,stream>>>(l2w,l2wT);
  k_gnn2<<<nt32,256,0,stream>>>(G1,trans,l2wT,l2b,G2,n);
  // ---- APPNP ----
  k_edgemode<<<1,256,0,stream>>>(ei,mode);
  hipMemsetAsync(ws + oDeg, 0, (size_t)n*4, stream);
  k_hist<<<2048,256,0,stream>>>(ei,mode,deg,e);
  k_dis<<<(n+255)/256,256,0,stream>>>(deg,dis,n);
  k_scan<<<1,1024,0,stream>>>(deg,rowp,n);
  k_copy<<<(n+255)/256,256,0,stream>>>(rowp,cur,n);
  k_fill<<<2048,256,0,stream>>>(ei,mode,dis,cur,col,wgt,e);
  const float* curx = G2;
  float* bufs[2] = {xA, xB};
  for (int it=0; it<10; ++it){
    float* nxt = bufs[it&1];
    k_appnp<<<(n+7)/8,256,0,stream>>>(curx,G2,nxt,rowp,col,wgt,dis,n);
    curx = nxt;
  }
  k_lsm<<<(n+7)/8,256,0,stream>>>(curx,(float*)d_out,n);
}

// Round 4
// 2355.738 us; speedup vs baseline: 2.0778x; 1.3705x over previous
//
#include <hip/hip_runtime.h>
#include <hip/hip_fp16.h>

#define NH 4
#define HD 64
#define MF 266
#define MP 288           // MF padded to multiple of 32 for MFMA K-steps
#define NB 96            // k_ctx partial blocks
#define DN 0.35355339059327373f
#define RATIO 0.06131393394849658f
#define EPSRF 1e-4f
#define REPS (RATIO*EPSRF)

typedef unsigned short u16;
typedef unsigned int u32;
typedef __attribute__((ext_vector_type(8))) short bf16x8;
typedef __attribute__((ext_vector_type(4))) float f32x4;
#define MFMA16(a,b,c) __builtin_amdgcn_mfma_f32_16x16x32_bf16(a,b,c,0,0,0)

__device__ __forceinline__ float bf2f(u16 u){ return __uint_as_float(((u32)u)<<16); }
__device__ __forceinline__ u16 f2bf(float f){ u32 u = __float_as_uint(f); u += 0x7FFFu + ((u>>16)&1u); return (u16)(u>>16); }
__device__ __forceinline__ u32 pack2bf(float a, float b){ return ((u32)f2bf(b)<<16) | f2bf(a); }
__device__ __forceinline__ float eluf(float x){ return x>0.f ? x : (expf(x)-1.f); }

// ---------------- weight/proj conversion to bf16 ----------------
__global__ void k_cvtw(const float* __restrict__ qw, const float* __restrict__ kw,
                       const float* __restrict__ vw, const float* __restrict__ lw,
                       const float* __restrict__ l2w, const float* __restrict__ proj,
                       u16* __restrict__ Wb, u16* __restrict__ projp, u16* __restrict__ l2wb){
  int i = blockIdx.x*256 + threadIdx.x;
  if (i < 262144){
    int sec = i>>16, r = i&65535;
    const float* s = sec==0?qw : sec==1?kw : sec==2?vw : lw;
    Wb[i] = f2bf(s[r]);
  }
  if (i < MP*64){
    int r = i>>6, c = i&63;
    projp[i] = f2bf(r < MF ? proj[r*64 + c] : 0.f);
  }
  if (i < 32*512) l2wb[i] = f2bf(l2w[i]);
}

// ---------------- K1: fused projection GEMM (MFMA, X staged once in LDS) ----------------
// C[n x 1024] = X @ W^T. Block = 128 rows; loops over all 8 col-tiles of 128.
__global__ __launch_bounds__(256) void k_proj(
    const float* __restrict__ x, const u16* __restrict__ Wb,
    const float* __restrict__ qb, const float* __restrict__ kb,
    const float* __restrict__ vb, const float* __restrict__ lb,
    u16* __restrict__ Q, u16* __restrict__ K, u16* __restrict__ V,
    u16* __restrict__ G1, int n)
{
  __shared__ u32 Xs[128*128];   // [row][word 0..127], word = col/2, XOR-swizzled
  const int tid = threadIdx.x;
  const int w = tid>>6, l = tid&63;
  const int wr = w>>1, wc = w&1;
  const int lm = l&15, lk = l>>4;
  const int row0 = blockIdx.x*128;
  // stage X (f32 -> bf16), one row per wave per step: fully coalesced 1KB/wave
  #pragma unroll 4
  for (int q=0;q<32;++q){
    int idx = q*256 + tid;          // 0..8191 float4s
    int r = idx>>6, c4 = idx&63;
    int rr = row0 + r; if (rr > n-1) rr = n-1;
    float4 v = *(const float4*)(x + (size_t)rr*256 + c4*4);
    int word = (c4*2) ^ ((r&7)<<2);
    *(uint2*)&Xs[r*128 + word] = make_uint2(pack2bf(v.x,v.y), pack2bf(v.z,v.w));
  }
  __syncthreads();
  #pragma unroll 1
  for (int ct=0; ct<8; ++ct){
    const int c0 = ct*128 + wc*64;
    f32x4 acc[4][4] = {};
    #pragma unroll 2
    for (int kt=0; kt<8; ++kt){
      bf16x8 Af[4], Bf[4];
      #pragma unroll
      for (int i=0;i<4;i++){
        const int rl = wr*64 + i*16 + lm;
        Af[i] = *(const bf16x8*)&Xs[rl*128 + ((kt*16 + lk*4) ^ ((rl&7)<<2))];
        Bf[i] = *(const bf16x8*)(Wb + (size_t)(c0 + i*16 + lm)*256 + kt*32 + lk*8);
      }
      #pragma unroll
      for (int i=0;i<4;i++)
        #pragma unroll
        for (int j=0;j<4;j++)
          acc[i][j] = MFMA16(Af[i], Bf[j], acc[i][j]);
    }
    const int sel = c0>>8;
    const float* bp = sel==0?qb : sel==1?kb : sel==2?vb : lb;
    u16* d3 = sel==0?Q : sel==1?K : sel==2?V : G1;
    #pragma unroll
    for (int j=0;j<4;j++){
      const int cc = (c0&255) + j*16 + lm;
      const float bias = bp[cc];
      const int hh = cc>>6, dd = cc&63;
      #pragma unroll
      for (int i=0;i<4;i++){
        #pragma unroll
        for (int jr=0;jr<4;jr++){
          const int r = row0 + wr*64 + i*16 + lk*4 + jr;
          if (r < n){
            u16 bv = f2bf(acc[i][j][jr] + bias);
            if (sel==3) d3[(size_t)r*256 + cc] = bv;
            else        d3[(((size_t)hh*n + r)<<6) + dd] = bv;
          }
        }
      }
    }
  }
}

// ---------------- V column sums (for EPS correction) ----------------
__global__ void k_vcs(const u16* __restrict__ Vb, float* __restrict__ vcs, int n){
  const int h = blockIdx.y, tid = threadIdx.x;
  const int d = tid&63, seg = tid>>6;
  float s = 0.f;
  for (int node = blockIdx.x*4 + seg; node < n; node += 256)
    s += bf2f(Vb[(((size_t)h*n + node)<<6) + d]);
  __shared__ float sm[4][64];
  sm[seg][d] = s; __syncthreads();
  if (tid < 64){
    float t2 = sm[0][tid]+sm[1][tid]+sm[2][tid]+sm[3][tid];
    atomicAdd(vcs + h*64 + tid, t2);
  }
}

// ---------------- K3: single-pass kp -> ksum0/ctx0 partials + global dash max ----------------
// grid (NB, NH). Each block handles all 288 m for its node-tiles; K/V read ONCE.
__global__ __launch_bounds__(256) void k_ctx(
    const u16* __restrict__ Kb, const u16* __restrict__ Vb,
    const u16* __restrict__ projp,
    float* __restrict__ ctxp, float* __restrict__ ksump,
    u32* __restrict__ kmaxg, int n)
{
  __shared__ u32 kpT[288*32];     // kp^T [m][node-word], XOR-swizzled
  __shared__ u16 Vt[64][72];      // V^T tile [d][node]
  __shared__ float redk[4][288];
  const int tid = threadIdx.x;
  const int w = tid>>6, l = tid&63;
  const int bb = blockIdx.x;
  const int h = blockIdx.y;
  const int lm = l&15, lk = l>>4;
  f32x4 cacc[18] = {};
  float ksa[18] = {};
  float mreg = -3.0e38f;
  const int ntile = (n+63)>>6;
  #pragma unroll 1
  for (int t=bb; t<ntile; t+=NB){
    const int n0 = t*64;
    __syncthreads();
    #pragma unroll
    for (int q=0;q<2;q++){
      int e8 = tid + q*256;
      int nn = e8>>3, d0 = (e8&7)*8;
      uint4 rv = make_uint4(0,0,0,0);
      if (n0+nn < n) rv = *(const uint4*)(Vb + (((size_t)h*n + n0+nn)<<6) + d0);
      const u16* pv = (const u16*)&rv;
      #pragma unroll
      for (int s=0;s<8;s++) Vt[d0+s][nn] = pv[s];
    }
    int rr = n0 + w*16 + lm; if (rr > n-1) rr = n-1;
    const u16* Kbase = Kb + (((size_t)h*n + rr)<<6);
    bf16x8 af0 = *(const bf16x8*)(Kbase + lk*8);
    bf16x8 af1 = *(const bf16x8*)(Kbase + 32 + lk*8);
    float dg = 0.f;
    #pragma unroll
    for (int i2=0;i2<8;i2++){
      float a = bf2f(((const u16*)&af0)[i2]);
      float b = bf2f(((const u16*)&af1)[i2]);
      dg += a*a + b*b;
    }
    dg += __shfl_xor(dg,16); dg += __shfl_xor(dg,32);
    dg *= 0.0625f;
    float dgr[4];
    #pragma unroll
    for (int j=0;j<4;j++) dgr[j] = __shfl(dg, lk*4+j, 16);
    #pragma unroll
    for (int mt=0; mt<18; ++mt){
      bf16x8 b0 = *(const bf16x8*)(projp + (size_t)(mt*16+lm)*64 + lk*8);
      bf16x8 b1 = *(const bf16x8*)(projp + (size_t)(mt*16+lm)*64 + 32 + lk*8);
      f32x4 D = {0,0,0,0};
      D = MFMA16(af0, b0, D);
      D = MFMA16(af1, b1, D);
      const int m = mt*16 + lm;
      const bool vm = m < MF;
      float colsum = 0.f;
      u32 pk0 = 0, pk1 = 0;
      #pragma unroll
      for (int j=0;j<4;j++){
        float ddash = DN * D[j];
        float kp = 0.f;
        if (vm && (n0 + w*16 + lk*4 + j) < n){
          kp = RATIO * __expf(ddash - dgr[j]);
          mreg = fmaxf(mreg, ddash);
          colsum += kp;
        }
        if (j<2) pk0 |= ((u32)f2bf(kp)) << (16*j);
        else     pk1 |= ((u32)f2bf(kp)) << (16*(j-2));
      }
      const int wn0 = w*8 + lk*2;
      *(uint2*)&kpT[m*32 + (wn0 ^ ((m&7)<<2))] = make_uint2(pk0, pk1);
      colsum += __shfl_xor(colsum,16); colsum += __shfl_xor(colsum,32);
      ksa[mt] += colsum;
    }
    __syncthreads();
    // PV: ctx0[m][d] += kp^T V ; wave w owns d-strip w*16..w*16+15
    #pragma unroll
    for (int mt=0; mt<18; ++mt){
      const int m = mt*16 + lm;
      #pragma unroll
      for (int ks=0;ks<2;++ks){
        bf16x8 a = *(const bf16x8*)&kpT[m*32 + ((ks*16 + lk*4) ^ ((m&7)<<2))];
        bf16x8 bv = *(const bf16x8*)&Vt[w*16+lm][ks*32 + lk*8];
        cacc[mt] = MFMA16(a, bv, cacc[mt]);
      }
    }
  }
  float* cp = ctxp + ((size_t)(h*NB + bb))*MP*64;
  #pragma unroll
  for (int mt=0;mt<18;++mt){
    #pragma unroll
    for (int j=0;j<4;j++){
      int m = mt*16 + lk*4 + j;
      cp[(size_t)m*64 + w*16 + lm] = cacc[mt][j];
    }
  }
  if (l < 16){
    #pragma unroll
    for (int mt=0;mt<18;++mt) redk[w][mt*16+lm] = ksa[mt];
  }
  __shared__ float redm[4];
  float mr = mreg;
  #pragma unroll
  for (int s=1;s<64;s<<=1) mr = fmaxf(mr, __shfl_xor(mr, s));
  if (l==0) redm[w] = mr;
  __syncthreads();
  for (int m2=tid; m2<MP; m2+=256){
    float s = redk[0][m2]+redk[1][m2]+redk[2][m2]+redk[3][m2];
    ksump[((size_t)(h*NB+bb))*MP + m2] = s;
  }
  if (tid==0){
    float bm = fmaxf(fmaxf(redm[0],redm[1]), fmaxf(redm[2],redm[3]));
    u32 b = __float_as_uint(bm);
    u32 enc = (b & 0x80000000u) ? ~b : (b | 0x80000000u);
    atomicMax(kmaxg + h, enc);
  }
}

// ---------------- K3b: reduce partials + apply max/EPS correction ----------------
__global__ void k_reduce(const float* __restrict__ ctxp, const float* __restrict__ ksump,
                         const u32* __restrict__ kmaxg, const float* __restrict__ vcs,
                         u16* __restrict__ ctxT, float* __restrict__ ksum, int n)
{
  const int T1 = NH*MP*64;
  int idx = blockIdx.x*256 + threadIdx.x;
  if (idx < T1){
    int h = idx/(MP*64), r = idx - h*MP*64, m = r>>6, d = r&63;
    u32 ee = kmaxg[h]; u32 b = (ee & 0x80000000u) ? (ee ^ 0x80000000u) : ~ee;
    float sc = __expf(-__uint_as_float(b));
    float s = 0.f;
    for (int bb=0; bb<NB; ++bb) s += ctxp[(((size_t)(h*NB+bb))*MP + m)*64 + d];
    float val = (m < MF) ? (sc*s + REPS*vcs[h*64 + d]) : 0.f;
    ctxT[((size_t)h*64 + d)*MP + m] = f2bf(val);
  } else if (idx < T1 + NH*MP){
    int k2 = idx - T1, h = k2/MP, m = k2 - h*MP;
    u32 ee = kmaxg[h]; u32 b = (ee & 0x80000000u) ? (ee ^ 0x80000000u) : ~ee;
    float sc = __expf(-__uint_as_float(b));
    float s = 0.f;
    for (int bb=0; bb<NB; ++bb) s += ksump[((size_t)(h*NB+bb))*MP + m];
    ksum[h*MP + m] = (m < MF) ? (sc*s + REPS*(float)n) : 0.f;
  }
}

// ---------------- K4: query path (MFMA) ----------------
__global__ __launch_bounds__(256) void k_qattn(
    const u16* __restrict__ Qb, const u16* __restrict__ projp,
    const u16* __restrict__ ctxT, const float* __restrict__ ksum,
    u16* __restrict__ trans, int n)
{
  __shared__ u16 qp_lds[4][16][296];
  const int tid = threadIdx.x;
  const int w = tid>>6, l = tid&63;
  const int h = blockIdx.y;
  const int nb = blockIdx.x*64 + w*16;
  const int lm = l&15, lk = l>>4;
  int rr = nb + lm; if (rr > n-1) rr = n-1;
  const u16* Qbase = Qb + (((size_t)h*n + rr)<<6);
  bf16x8 af0 = *(const bf16x8*)(Qbase + lk*8);
  bf16x8 af1 = *(const bf16x8*)(Qbase + 32 + lk*8);
  float dg = 0.f;
  #pragma unroll
  for (int i2=0;i2<8;i2++){
    float a = bf2f(((const u16*)&af0)[i2]);
    float b = bf2f(((const u16*)&af1)[i2]);
    dg += a*a + b*b;
  }
  dg += __shfl_xor(dg,16); dg += __shfl_xor(dg,32);
  dg *= 0.0625f;
  float dgr[4];
  #pragma unroll
  for (int j=0;j<4;j++) dgr[j] = __shfl(dg, lk*4+j, 16);
  f32x4 D[17];
  #pragma unroll
  for (int mt=0;mt<17;++mt){
    bf16x8 b0 = *(const bf16x8*)(projp + (size_t)(mt*16+lm)*64 + lk*8);
    bf16x8 b1 = *(const bf16x8*)(projp + (size_t)(mt*16+lm)*64 + 32 + lk*8);
    f32x4 z = {0,0,0,0};
    z = MFMA16(af0, b0, z);
    z = MFMA16(af1, b1, z);
    D[mt] = z;
  }
  float rmax[4] = {-3.0e38f,-3.0e38f,-3.0e38f,-3.0e38f};
  #pragma unroll
  for (int mt=0;mt<17;++mt){
    const bool vm = (mt<16) || (lm<10);
    #pragma unroll
    for (int j=0;j<4;j++){
      float dd = DN*D[mt][j];
      if (vm) rmax[j] = fmaxf(rmax[j], dd);
    }
  }
  #pragma unroll
  for (int j=0;j<4;j++){
    #pragma unroll
    for (int s=1;s<16;s<<=1) rmax[j] = fmaxf(rmax[j], __shfl_xor(rmax[j], s));
  }
  float den[4] = {0,0,0,0};
  #pragma unroll
  for (int mt=0;mt<17;++mt){
    const int m = mt*16 + lm;
    const float ksm = ksum[h*MP + m];
    #pragma unroll
    for (int j=0;j<4;j++){
      float qp = RATIO*(__expf(DN*D[mt][j] - dgr[j] - rmax[j]) + EPSRF);
      den[j] += qp * ksm;
      qp_lds[w][lk*4+j][m] = f2bf(qp);
    }
  }
  #pragma unroll
  for (int j=0;j<4;j++) qp_lds[w][lk*4+j][272+lm] = 0;
  #pragma unroll
  for (int j=0;j<4;j++){
    #pragma unroll
    for (int s=1;s<16;s<<=1) den[j] += __shfl_xor(den[j], s);
  }
  __syncthreads();
  f32x4 o[4] = {{0,0,0,0},{0,0,0,0},{0,0,0,0},{0,0,0,0}};
  #pragma unroll
  for (int ks=0;ks<9;++ks){
    bf16x8 av = *(const bf16x8*)&qp_lds[w][lm][ks*32 + lk*8];
    #pragma unroll
    for (int dt=0;dt<4;++dt){
      bf16x8 bv = *(const bf16x8*)(ctxT + (size_t)(h*64 + dt*16 + lm)*MP + ks*32 + lk*8);
      o[dt] = MFMA16(av, bv, o[dt]);
    }
  }
  #pragma unroll
  for (int j=0;j<4;j++){
    const int node = nb + lk*4 + j;
    if (node < n){
      const float dv = 1.f/den[j];
      #pragma unroll
      for (int dt=0;dt<4;++dt)
        trans[(size_t)node*256 + h*64 + dt*16 + lm] = f2bf(o[dt][j]*dv);
    }
  }
}

// ---------------- K5: cat -> elu -> lin2 -> elu (MFMA) ----------------
__global__ __launch_bounds__(256) void k_gnn2(
    const u16* __restrict__ G1, const u16* __restrict__ trans,
    const u16* __restrict__ l2wb, const float* __restrict__ l2b,
    float* __restrict__ G2, u16* __restrict__ xb0, int n)
{
  __shared__ u32 cat[64*256];   // 64 nodes x 512 bf16 (256 words/row), swizzled
  const int tid = threadIdx.x;
  const int w = tid>>6, l = tid&63;
  const int lm = l&15, lk = l>>4;
  const int n0 = blockIdx.x*64;
  #pragma unroll
  for (int src=0; src<2; ++src){
    const u16* S = src ? trans : G1;
    #pragma unroll
    for (int q=0;q<8;++q){
      int idx = q*256 + tid;
      int row = idx>>5, v8 = idx&31;
      int rr = n0+row; if (rr > n-1) rr = n-1;
      uint4 raw = *(const uint4*)(S + (size_t)rr*256 + v8*8);
      const u16* p = (const u16*)&raw;
      u32 o2[4];
      #pragma unroll
      for (int t2=0;t2<4;++t2)
        o2[t2] = pack2bf(eluf(bf2f(p[t2*2])), eluf(bf2f(p[t2*2+1])));
      int word = (v8*4 + src*128) ^ ((row&7)<<2);
      *(uint4*)&cat[row*256 + word] = *(uint4*)o2;
    }
  }
  __syncthreads();
  f32x4 acc[2] = {{0,0,0,0},{0,0,0,0}};
  const int rowl = w*16 + lm;
  #pragma unroll 4
  for (int kt=0; kt<16; ++kt){
    bf16x8 a = *(const bf16x8*)&cat[rowl*256 + ((kt*16 + lk*4) ^ ((rowl&7)<<2))];
    #pragma unroll
    for (int jj=0;jj<2;++jj){
      bf16x8 b = *(const bf16x8*)(l2wb + (size_t)(jj*16+lm)*512 + kt*32 + lk*8);
      acc[jj] = MFMA16(a, b, acc[jj]);
    }
  }
  #pragma unroll
  for (int jj=0;jj<2;++jj){
    const int o = jj*16 + lm;
    const float bias = l2b[o];
    #pragma unroll
    for (int jr=0;jr<4;++jr){
      const int node = n0 + w*16 + lk*4 + jr;
      if (node < n){
        float v = eluf(acc[jj][jr] + bias);
        G2[(size_t)node*32 + o] = v;
        xb0[(size_t)node*32 + o] = f2bf(v);
      }
    }
  }
}

// ---------------- edge layout detect ----------------
__global__ void k_edgemode(const int* __restrict__ ei, int* __restrict__ mode){
  __shared__ int any;
  if (threadIdx.x==0) any = 0;
  __syncthreads();
  if (ei[threadIdx.x*2+1] != 0) any = 1;
  __syncthreads();
  if (threadIdx.x==0) *mode = any;
}
__device__ __forceinline__ int edge_at(const int* ei, int mode, size_t idx){
  if (mode) return ei[idx];
  return (int)((const long long*)ei)[idx];
}

// ---------------- CSR build ----------------
__global__ void k_hist(const int* __restrict__ ei, const int* __restrict__ mode,
                       u32* __restrict__ deg, int e){
  const int md = *mode;
  for (size_t i = (size_t)blockIdx.x*blockDim.x + threadIdx.x; i < (size_t)e; i += (size_t)gridDim.x*blockDim.x)
    atomicAdd(&deg[edge_at(ei, md, (size_t)e + i)], 1u);
}
__global__ void k_dis(const u32* __restrict__ deg, float* __restrict__ dis, int n){
  int i = blockIdx.x*256 + threadIdx.x;
  if (i<n) dis[i] = rsqrtf((float)(deg[i] + 1u));
}
__global__ __launch_bounds__(1024) void k_scan(const u32* __restrict__ deg, u32* __restrict__ rowp, int n){
  __shared__ u32 wsum[16];
  __shared__ u32 carry;
  const int tid = threadIdx.x, lane = tid&63, wv = tid>>6;
  if (tid==0){ carry = 0u; rowp[0] = 0u; }
  __syncthreads();
  for (int base=0; base<n; base+=1024){
    int i = base + tid;
    u32 v = (i<n)? deg[i] : 0u;
    u32 s = v;
    #pragma unroll
    for (int off=1; off<64; off<<=1){
      u32 t = __shfl_up(s, off, 64);
      if (lane >= off) s += t;
    }
    if (lane==63) wsum[wv] = s;
    __syncthreads();
    if (wv==0){
      u32 ws = (lane<16)? wsum[lane] : 0u;
      #pragma unroll
      for (int off=1; off<16; off<<=1){
        u32 t = __shfl_up(ws, off, 64);
        if (lane >= off) ws += t;
      }
      if (lane<16) wsum[lane] = ws;
    }
    __syncthreads();
    u32 pre = carry + (wv ? wsum[wv-1] : 0u);
    if (i<n) rowp[i+1] = pre + s;
    __syncthreads();
    if (tid==0) carry += wsum[15];
    __syncthreads();
  }
}
__global__ void k_copy(const u32* __restrict__ a, u32* __restrict__ b, int n){
  int i = blockIdx.x*256 + threadIdx.x; if (i<n) b[i]=a[i];
}
__global__ void k_fill(const int* __restrict__ ei, const int* __restrict__ mode,
                       const float* __restrict__ dis,
                       u32* __restrict__ cur, uint2* __restrict__ cw, int e){
  const int md = *mode;
  for (size_t i = (size_t)blockIdx.x*blockDim.x + threadIdx.x; i < (size_t)e; i += (size_t)gridDim.x*blockDim.x){
    int s = edge_at(ei, md, i);
    int t = edge_at(ei, md, (size_t)e + i);
    u32 pos = atomicAdd(&cur[t], 1u);
    cw[pos] = make_uint2((u32)s, __float_as_uint(dis[s]*dis[t]));
  }
}

// ---------------- APPNP iteration (bf16 x, packed col+wgt) ----------------
__global__ __launch_bounds__(256) void k_appnp(
    const u16* __restrict__ xin, const float* __restrict__ hbuf,
    u16* __restrict__ xout, const u32* __restrict__ rowp,
    const uint2* __restrict__ cw, const float* __restrict__ dis, int n)
{
  const int g = threadIdx.x>>5, j = threadIdx.x&31;
  const int node = blockIdx.x*8 + g;
  if (node >= n) return;
  float d0 = dis[node];
  float acc = d0*d0*bf2f(xin[((size_t)node<<5) + j]);
  u32 r0 = rowp[node], r1 = rowp[node+1];
  u32 k = r0;
  for (; k+2 <= r1; k += 2){
    uint2 a = cw[k], b = cw[k+1];
    float xa = bf2f(xin[((size_t)a.x<<5) + j]);
    float xb = bf2f(xin[((size_t)b.x<<5) + j]);
    acc += __uint_as_float(a.y)*xa;
    acc += __uint_as_float(b.y)*xb;
  }
  if (k < r1){
    uint2 a = cw[k];
    acc += __uint_as_float(a.y)*bf2f(xin[((size_t)a.x<<5) + j]);
  }
  xout[((size_t)node<<5)+j] = f2bf(0.9f*acc + 0.1f*hbuf[((size_t)node<<5)+j]);
}

// ---------------- log_softmax + raw ----------------
__global__ __launch_bounds__(256) void k_lsm(const u16* __restrict__ xin, float* __restrict__ out, int n){
  const int g = threadIdx.x>>5, j = threadIdx.x&31;
  const int node = blockIdx.x*8 + g;
  if (node>=n) return;
  float v = bf2f(xin[((size_t)node<<5)+j]);
  float m = v;
  #pragma unroll
  for (int o=16;o;o>>=1) m = fmaxf(m, __shfl_xor(m, o, 32));
  float s = expf(v - m);
  #pragma unroll
  for (int o=16;o;o>>=1) s += __shfl_xor(s, o, 32);
  out[((size_t)node<<5)+j] = v - m - logf(s);
  out[(size_t)n*32 + ((size_t)node<<5)+j] = v;
}

extern "C" void kernel_launch(void* const* d_in, const int* in_sizes, int n_in,
                              void* d_out, int out_size, void* d_ws, size_t ws_size,
                              hipStream_t stream)
{
  const float* x   = (const float*)d_in[0];
  const int*   ei  = (const int*)  d_in[1];
  const float* l1w = (const float*)d_in[2];
  const float* l1b = (const float*)d_in[3];
  const float* l2w = (const float*)d_in[4];
  const float* l2b = (const float*)d_in[5];
  const float* qw  = (const float*)d_in[6];
  const float* qb  = (const float*)d_in[7];
  const float* kw  = (const float*)d_in[8];
  const float* kb  = (const float*)d_in[9];
  const float* vw  = (const float*)d_in[10];
  const float* vb  = (const float*)d_in[11];
  const float* proj= (const float*)d_in[12];
  const int n = in_sizes[0] / 256;
  const int e = in_sizes[1] / 2;

  char* ws = (char*)d_ws;
  auto au = [](size_t v){ return (v + 255) & ~(size_t)255; };
  const size_t bQ = (size_t)n * 512;
  const size_t oQ = 0;
  const size_t oK = au(oQ + bQ);
  const size_t oV = au(oK + bQ);
  const size_t oG1 = au(oV + bQ);
  const size_t oCtxp = au(oG1 + bQ);
  const size_t bCtxp = (size_t)NH*NB*MP*64*4;
  const size_t oKsump = au(oCtxp + bCtxp);
  const size_t bKsump = (size_t)NH*NB*MP*4;
  const size_t oCtxT = au(oKsump + bKsump);
  const size_t oKsum = au(oCtxT + (size_t)NH*64*MP*2);
  const size_t oKmax = au(oKsum + (size_t)NH*MP*4);
  const size_t oVcs  = oKmax + 256;
  const size_t oMode = oVcs + 1024;
  const size_t oL2wb = au(oMode + 256);
  const size_t oWb   = au(oL2wb + 32768);
  const size_t oProjp= au(oWb + (size_t)1024*256*2);
  // aliases: trans -> K region (K dead after k_ctx); G2/xb/appnp scratch -> Q region
  const size_t oTrans = oK;
  const size_t oG2 = oQ;
  const size_t oXb0 = au(oG2 + (size_t)n*32*4);
  const size_t oXbA = au(oXb0 + (size_t)n*32*2);
  const size_t oXbB = au(oXbA + (size_t)n*32*2);
  const size_t oDeg = au(oXbB + (size_t)n*32*2);
  const size_t oDis = au(oDeg + (size_t)n*4);
  const size_t oRowp= au(oDis + (size_t)n*4);
  const size_t oCur = au(oRowp + (size_t)(n+1)*4);
  const size_t oCw  = oV;     // uint2 per edge, V dead after k_ctx/k_vcs
  (void)ws_size; (void)n_in; (void)out_size;

  u16* Q  = (u16*)(ws + oQ);
  u16* Kb = (u16*)(ws + oK);
  u16* Vb = (u16*)(ws + oV);
  u16* G1 = (u16*)(ws + oG1);
  float* ctxp = (float*)(ws + oCtxp);
  float* ksump= (float*)(ws + oKsump);
  u16*  ctxT  = (u16*)(ws + oCtxT);
  float* ksum = (float*)(ws + oKsum);
  u32*  kmax  = (u32*)(ws + oKmax);
  float* Vcs  = (float*)(ws + oVcs);
  int*  mode  = (int*)(ws + oMode);
  u16*  l2wb  = (u16*)(ws + oL2wb);
  u16*  Wb    = (u16*)(ws + oWb);
  u16*  projp = (u16*)(ws + oProjp);
  u16* trans  = (u16*)(ws + oTrans);
  float* G2   = (float*)(ws + oG2);
  u16* xb0    = (u16*)(ws + oXb0);
  u16* xbA    = (u16*)(ws + oXbA);
  u16* xbB    = (u16*)(ws + oXbB);
  u32* deg    = (u32*)(ws + oDeg);
  float* dis  = (float*)(ws + oDis);
  u32* rowp   = (u32*)(ws + oRowp);
  u32* cur    = (u32*)(ws + oCur);
  uint2* cw   = (uint2*)(ws + oCw);

  k_cvtw<<<1024,256,0,stream>>>(qw,kw,vw,l1w,l2w,proj,Wb,projp,l2wb);
  k_proj<<<(n+127)/128,256,0,stream>>>(x,Wb,qb,kb,vb,l1b,Q,Kb,Vb,G1,n);
  hipMemsetAsync(ws + oKmax, 0, 16, stream);
  hipMemsetAsync(ws + oVcs, 0, 1024, stream);
  k_vcs<<<dim3(64,4),256,0,stream>>>(Vb,Vcs,n);
  k_ctx<<<dim3(NB,NH),256,0,stream>>>(Kb,Vb,projp,ctxp,ksump,kmax,n);
  {
    int tot = NH*MP*64 + NH*MP;
    k_reduce<<<(tot+255)/256,256,0,stream>>>(ctxp,ksump,kmax,Vcs,ctxT,ksum,n);
  }
  k_qattn<<<dim3((n+63)/64,4),256,0,stream>>>(Q,projp,ctxT,ksum,trans,n);
  k_gnn2<<<(n+63)/64,256,0,stream>>>(G1,trans,l2wb,l2b,G2,xb0,n);
  // ---- APPNP ----
  k_edgemode<<<1,256,0,stream>>>(ei,mode);
  hipMemsetAsync(ws + oDeg, 0, (size_t)n*4, stream);
  k_hist<<<2048,256,0,stream>>>(ei,mode,deg,e);
  k_dis<<<(n+255)/256,256,0,stream>>>(deg,dis,n);
  k_scan<<<1,1024,0,stream>>>(deg,rowp,n);
  k_copy<<<(n+255)/256,256,0,stream>>>(rowp,cur,n);
  k_fill<<<2048,256,0,stream>>>(ei,mode,dis,cur,cw,e);
  const u16* curx = xb0;
  u16* bufs[2] = {xbA, xbB};
  for (int it=0; it<10; ++it){
    u16* nxt = bufs[it&1];
    k_appnp<<<(n+7)/8,256,0,stream>>>(curx,G2,nxt,rowp,cw,dis,n);
    curx = nxt;
  }
  k_lsm<<<(n+7)/8,256,0,stream>>>(curx,(float*)d_out,n);
}

// Round 5
// 2052.029 us; speedup vs baseline: 2.3853x; 1.1480x over previous
//
#include <hip/hip_runtime.h>
#include <hip/hip_fp16.h>

#define NH 4
#define HD 64
#define MF 266
#define MP 288           // MF padded to multiple of 32 for MFMA K-steps
#define NB 192           // k_ctx partial blocks
#define DN 0.35355339059327373f
#define RATIO 0.06131393394849658f
#define EPSRF 1e-4f
#define REPS (RATIO*EPSRF)

typedef unsigned short u16;
typedef unsigned int u32;
typedef __attribute__((ext_vector_type(8))) short bf16x8;
typedef __attribute__((ext_vector_type(4))) float f32x4;
#define MFMA16(a,b,c) __builtin_amdgcn_mfma_f32_16x16x32_bf16(a,b,c,0,0,0)

__device__ __forceinline__ float bf2f(u16 u){ return __uint_as_float(((u32)u)<<16); }
__device__ __forceinline__ u16 f2bf(float f){ u32 u = __float_as_uint(f); u += 0x7FFFu + ((u>>16)&1u); return (u16)(u>>16); }
__device__ __forceinline__ u32 pack2bf(float a, float b){ return ((u32)f2bf(b)<<16) | f2bf(a); }
__device__ __forceinline__ float eluf(float x){ return x>0.f ? x : (expf(x)-1.f); }

// ---------------- weight/proj conversion to bf16 ----------------
__global__ void k_cvtw(const float* __restrict__ qw, const float* __restrict__ kw,
                       const float* __restrict__ vw, const float* __restrict__ lw,
                       const float* __restrict__ l2w, const float* __restrict__ proj,
                       u16* __restrict__ Wb, u16* __restrict__ projp, u16* __restrict__ l2wb){
  int i = blockIdx.x*256 + threadIdx.x;
  if (i < 262144){
    int sec = i>>16, r = i&65535;
    const float* s = sec==0?qw : sec==1?kw : sec==2?vw : lw;
    Wb[i] = f2bf(s[r]);
  }
  if (i < MP*64){
    int r = i>>6, c = i&63;
    projp[i] = f2bf(r < MF ? proj[r*64 + c] : 0.f);
  }
  if (i < 32*512) l2wb[i] = f2bf(l2w[i]);
}

// ---------------- K1: fused projection GEMM (MFMA, X staged once, 8 waves) ----------------
// C[n x 1024] = X @ W^T. Block = 128 rows, 512 threads; loops over 8 col-tiles of 128.
// Wave w: rows wr*64 (wr=w>>2), cols wc*32 within tile (wc=w&3).
__global__ __launch_bounds__(512,4) void k_proj(
    const float* __restrict__ x, const u16* __restrict__ Wb,
    const float* __restrict__ qb, const float* __restrict__ kb,
    const float* __restrict__ vb, const float* __restrict__ lb,
    u16* __restrict__ Q, u16* __restrict__ K, u16* __restrict__ V,
    u16* __restrict__ G1, int n)
{
  __shared__ u32 Xs[128*128];   // [row][word 0..127], word = col/2, XOR-swizzled
  const int tid = threadIdx.x;
  const int w = tid>>6, l = tid&63;
  const int wr = w>>2, wc = w&3;
  const int lm = l&15, lk = l>>4;
  const int row0 = blockIdx.x*128;
  #pragma unroll 4
  for (int q=0;q<16;++q){
    int idx = q*512 + tid;          // 0..8191 float4s
    int r = idx>>6, c4 = idx&63;
    int rr = row0 + r; if (rr > n-1) rr = n-1;
    float4 v = *(const float4*)(x + (size_t)rr*256 + c4*4);
    int word = (c4*2) ^ ((r&7)<<2);
    *(uint2*)&Xs[r*128 + word] = make_uint2(pack2bf(v.x,v.y), pack2bf(v.z,v.w));
  }
  __syncthreads();
  #pragma unroll 1
  for (int ct=0; ct<8; ++ct){
    const int c0 = ct*128 + wc*32;
    f32x4 acc[4][2] = {};
    #pragma unroll 2
    for (int kt=0; kt<8; ++kt){
      bf16x8 Af[4], Bf[2];
      #pragma unroll
      for (int jj=0;jj<2;jj++)
        Bf[jj] = *(const bf16x8*)(Wb + (size_t)(c0 + jj*16 + lm)*256 + kt*32 + lk*8);
      #pragma unroll
      for (int i=0;i<4;i++){
        const int rl = wr*64 + i*16 + lm;
        Af[i] = *(const bf16x8*)&Xs[rl*128 + ((kt*16 + lk*4) ^ ((rl&7)<<2))];
      }
      #pragma unroll
      for (int i=0;i<4;i++)
        #pragma unroll
        for (int jj=0;jj<2;jj++)
          acc[i][jj] = MFMA16(Af[i], Bf[jj], acc[i][jj]);
    }
    const int sel = c0>>8;
    const float* bp = sel==0?qb : sel==1?kb : sel==2?vb : lb;
    u16* d3 = sel==0?Q : sel==1?K : sel==2?V : G1;
    u32* dst32 = (u32*)d3;
    const bool even = (lm&1)==0;
    #pragma unroll
    for (int jj=0;jj<2;jj++){
      const int cc = (c0&255) + jj*16 + lm;
      const float bias = bp[cc];
      const int ccA = cc & ~1;
      const int hh = ccA>>6, dd = ccA&63;
      #pragma unroll
      for (int i=0;i<4;i++){
        const int rb = row0 + wr*64 + i*16 + lk*4;
        u32 m01 = pack2bf(acc[i][jj][0]+bias, acc[i][jj][1]+bias);
        u32 m23 = pack2bf(acc[i][jj][2]+bias, acc[i][jj][3]+bias);
        u32 oa = __shfl_xor(m01,1);
        u32 ob = __shfl_xor(m23,1);
        // even lane: rows rb+0,rb+1 ; odd lane: rows rb+2,rb+3
        u32 wA = even ? ((m01 & 0xffffu) | ((oa & 0xffffu)<<16))
                      : ((ob  & 0xffffu) | ((m23 & 0xffffu)<<16));
        u32 wB = even ? ((m01 >> 16) | (oa & 0xffff0000u))
                      : ((ob  >> 16) | (m23 & 0xffff0000u));
        const int rA = rb + (even ? 0 : 2);
        const int rB = rA + 1;
        if (sel==3){
          if (rA < n) dst32[(size_t)rA*128 + (ccA>>1)] = wA;
          if (rB < n) dst32[(size_t)rB*128 + (ccA>>1)] = wB;
        } else {
          if (rA < n) dst32[(((size_t)hh*n + rA)<<5) + (dd>>1)] = wA;
          if (rB < n) dst32[(((size_t)hh*n + rB)<<5) + (dd>>1)] = wB;
        }
      }
    }
  }
}

// ---------------- V column sums (for EPS correction) ----------------
__global__ void k_vcs(const u16* __restrict__ Vb, float* __restrict__ vcs, int n){
  const int h = blockIdx.y, tid = threadIdx.x;
  const int d = tid&63, seg = tid>>6;
  float s = 0.f;
  for (int node = blockIdx.x*4 + seg; node < n; node += 256)
    s += bf2f(Vb[(((size_t)h*n + node)<<6) + d]);
  __shared__ float sm[4][64];
  sm[seg][d] = s; __syncthreads();
  if (tid < 64){
    float t2 = sm[0][tid]+sm[1][tid]+sm[2][tid]+sm[3][tid];
    atomicAdd(vcs + h*64 + tid, t2);
  }
}

// ---------------- K3: single-pass kp -> ksum0/ctx0 partials + global dash max ----------------
// grid (NB, NH). Each block handles all 288 m for its node-tiles; K/V read ONCE.
__global__ __launch_bounds__(256) void k_ctx(
    const u16* __restrict__ Kb, const u16* __restrict__ Vb,
    const u16* __restrict__ projp,
    float* __restrict__ ctxp, float* __restrict__ ksump,
    u32* __restrict__ kmaxg, int n)
{
  __shared__ u32 kpT[288*32];     // kp^T [m][node-word], XOR-swizzled
  __shared__ u16 Vt[64][72];      // V^T tile [d][node]
  __shared__ float redk[4][288];
  const int tid = threadIdx.x;
  const int w = tid>>6, l = tid&63;
  const int bb = blockIdx.x;
  const int h = blockIdx.y;
  const int lm = l&15, lk = l>>4;
  f32x4 cacc[18] = {};
  float ksa[18] = {};
  float mreg = -3.0e38f;
  const int ntile = (n+63)>>6;
  #pragma unroll 1
  for (int t=bb; t<ntile; t+=NB){
    const int n0 = t*64;
    __syncthreads();
    #pragma unroll
    for (int q=0;q<2;q++){
      int e8 = tid + q*256;
      int nn = e8>>3, d0 = (e8&7)*8;
      uint4 rv = make_uint4(0,0,0,0);
      if (n0+nn < n) rv = *(const uint4*)(Vb + (((size_t)h*n + n0+nn)<<6) + d0);
      const u16* pv = (const u16*)&rv;
      #pragma unroll
      for (int s=0;s<8;s++) Vt[d0+s][nn] = pv[s];
    }
    int rr = n0 + w*16 + lm; if (rr > n-1) rr = n-1;
    const u16* Kbase = Kb + (((size_t)h*n + rr)<<6);
    bf16x8 af0 = *(const bf16x8*)(Kbase + lk*8);
    bf16x8 af1 = *(const bf16x8*)(Kbase + 32 + lk*8);
    float dg = 0.f;
    #pragma unroll
    for (int i2=0;i2<8;i2++){
      float a = bf2f(((const u16*)&af0)[i2]);
      float b = bf2f(((const u16*)&af1)[i2]);
      dg += a*a + b*b;
    }
    dg += __shfl_xor(dg,16); dg += __shfl_xor(dg,32);
    dg *= 0.0625f;
    float dgr[4];
    #pragma unroll
    for (int j=0;j<4;j++) dgr[j] = __shfl(dg, lk*4+j, 16);
    #pragma unroll
    for (int mt=0; mt<18; ++mt){
      bf16x8 b0 = *(const bf16x8*)(projp + (size_t)(mt*16+lm)*64 + lk*8);
      bf16x8 b1 = *(const bf16x8*)(projp + (size_t)(mt*16+lm)*64 + 32 + lk*8);
      f32x4 D = {0,0,0,0};
      D = MFMA16(af0, b0, D);
      D = MFMA16(af1, b1, D);
      const int m = mt*16 + lm;
      const bool vm = m < MF;
      float colsum = 0.f;
      u32 pk0 = 0, pk1 = 0;
      #pragma unroll
      for (int j=0;j<4;j++){
        float ddash = DN * D[j];
        float kp = 0.f;
        if (vm && (n0 + w*16 + lk*4 + j) < n){
          kp = RATIO * __expf(ddash - dgr[j]);
          mreg = fmaxf(mreg, ddash);
          colsum += kp;
        }
        if (j<2) pk0 |= ((u32)f2bf(kp)) << (16*j);
        else     pk1 |= ((u32)f2bf(kp)) << (16*(j-2));
      }
      const int wn0 = w*8 + lk*2;
      *(uint2*)&kpT[m*32 + (wn0 ^ ((m&7)<<2))] = make_uint2(pk0, pk1);
      colsum += __shfl_xor(colsum,16); colsum += __shfl_xor(colsum,32);
      ksa[mt] += colsum;
    }
    __syncthreads();
    // PV: ctx0[m][d] += kp^T V ; wave w owns d-strip w*16..w*16+15
    #pragma unroll
    for (int mt=0; mt<18; ++mt){
      const int m = mt*16 + lm;
      #pragma unroll
      for (int ks=0;ks<2;++ks){
        bf16x8 a = *(const bf16x8*)&kpT[m*32 + ((ks*16 + lk*4) ^ ((m&7)<<2))];
        bf16x8 bv = *(const bf16x8*)&Vt[w*16+lm][ks*32 + lk*8];
        cacc[mt] = MFMA16(a, bv, cacc[mt]);
      }
    }
  }
  float* cp = ctxp + ((size_t)(h*NB + bb))*MP*64;
  #pragma unroll
  for (int mt=0;mt<18;++mt){
    #pragma unroll
    for (int j=0;j<4;j++){
      int m = mt*16 + lk*4 + j;
      cp[(size_t)m*64 + w*16 + lm] = cacc[mt][j];
    }
  }
  if (l < 16){
    #pragma unroll
    for (int mt=0;mt<18;++mt) redk[w][mt*16+lm] = ksa[mt];
  }
  __shared__ float redm[4];
  float mr = mreg;
  #pragma unroll
  for (int s=1;s<64;s<<=1) mr = fmaxf(mr, __shfl_xor(mr, s));
  if (l==0) redm[w] = mr;
  __syncthreads();
  for (int m2=tid; m2<MP; m2+=256){
    float s = redk[0][m2]+redk[1][m2]+redk[2][m2]+redk[3][m2];
    ksump[((size_t)(h*NB+bb))*MP + m2] = s;
  }
  if (tid==0){
    float bm = fmaxf(fmaxf(redm[0],redm[1]), fmaxf(redm[2],redm[3]));
    u32 b = __float_as_uint(bm);
    u32 enc = (b & 0x80000000u) ? ~b : (b | 0x80000000u);
    atomicMax(kmaxg + h, enc);
  }
}

// ---------------- K3b: reduce partials + apply max/EPS correction ----------------
__global__ void k_reduce(const float* __restrict__ ctxp, const float* __restrict__ ksump,
                         const u32* __restrict__ kmaxg, const float* __restrict__ vcs,
                         u16* __restrict__ ctxT, float* __restrict__ ksum, int n)
{
  const int T1 = NH*MP*64;
  int idx = blockIdx.x*256 + threadIdx.x;
  if (idx < T1){
    int h = idx/(MP*64), r = idx - h*MP*64, m = r>>6, d = r&63;
    u32 ee = kmaxg[h]; u32 b = (ee & 0x80000000u) ? (ee ^ 0x80000000u) : ~ee;
    float sc = __expf(-__uint_as_float(b));
    float s = 0.f;
    for (int bb=0; bb<NB; ++bb) s += ctxp[(((size_t)(h*NB+bb))*MP + m)*64 + d];
    float val = (m < MF) ? (sc*s + REPS*vcs[h*64 + d]) : 0.f;
    ctxT[((size_t)h*64 + d)*MP + m] = f2bf(val);
  } else if (idx < T1 + NH*MP){
    int k2 = idx - T1, h = k2/MP, m = k2 - h*MP;
    u32 ee = kmaxg[h]; u32 b = (ee & 0x80000000u) ? (ee ^ 0x80000000u) : ~ee;
    float sc = __expf(-__uint_as_float(b));
    float s = 0.f;
    for (int bb=0; bb<NB; ++bb) s += ksump[((size_t)(h*NB+bb))*MP + m];
    ksum[h*MP + m] = (m < MF) ? (sc*s + REPS*(float)n) : 0.f;
  }
}

// ---------------- K4: query path (MFMA) ----------------
__global__ __launch_bounds__(256) void k_qattn(
    const u16* __restrict__ Qb, const u16* __restrict__ projp,
    const u16* __restrict__ ctxT, const float* __restrict__ ksum,
    u16* __restrict__ trans, int n)
{
  __shared__ u16 qp_lds[4][16][296];
  const int tid = threadIdx.x;
  const int w = tid>>6, l = tid&63;
  const int h = blockIdx.y;
  const int nb = blockIdx.x*64 + w*16;
  const int lm = l&15, lk = l>>4;
  int rr = nb + lm; if (rr > n-1) rr = n-1;
  const u16* Qbase = Qb + (((size_t)h*n + rr)<<6);
  bf16x8 af0 = *(const bf16x8*)(Qbase + lk*8);
  bf16x8 af1 = *(const bf16x8*)(Qbase + 32 + lk*8);
  float dg = 0.f;
  #pragma unroll
  for (int i2=0;i2<8;i2++){
    float a = bf2f(((const u16*)&af0)[i2]);
    float b = bf2f(((const u16*)&af1)[i2]);
    dg += a*a + b*b;
  }
  dg += __shfl_xor(dg,16); dg += __shfl_xor(dg,32);
  dg *= 0.0625f;
  float dgr[4];
  #pragma unroll
  for (int j=0;j<4;j++) dgr[j] = __shfl(dg, lk*4+j, 16);
  f32x4 D[17];
  #pragma unroll
  for (int mt=0;mt<17;++mt){
    bf16x8 b0 = *(const bf16x8*)(projp + (size_t)(mt*16+lm)*64 + lk*8);
    bf16x8 b1 = *(const bf16x8*)(projp + (size_t)(mt*16+lm)*64 + 32 + lk*8);
    f32x4 z = {0,0,0,0};
    z = MFMA16(af0, b0, z);
    z = MFMA16(af1, b1, z);
    D[mt] = z;
  }
  float rmax[4] = {-3.0e38f,-3.0e38f,-3.0e38f,-3.0e38f};
  #pragma unroll
  for (int mt=0;mt<17;++mt){
    const bool vm = (mt<16) || (lm<10);
    #pragma unroll
    for (int j=0;j<4;j++){
      float dd = DN*D[mt][j];
      if (vm) rmax[j] = fmaxf(rmax[j], dd);
    }
  }
  #pragma unroll
  for (int j=0;j<4;j++){
    #pragma unroll
    for (int s=1;s<16;s<<=1) rmax[j] = fmaxf(rmax[j], __shfl_xor(rmax[j], s));
  }
  float den[4] = {0,0,0,0};
  #pragma unroll
  for (int mt=0;mt<17;++mt){
    const int m = mt*16 + lm;
    const float ksm = ksum[h*MP + m];
    #pragma unroll
    for (int j=0;j<4;j++){
      float qp = RATIO*(__expf(DN*D[mt][j] - dgr[j] - rmax[j]) + EPSRF);
      den[j] += qp * ksm;
      qp_lds[w][lk*4+j][m] = f2bf(qp);
    }
  }
  #pragma unroll
  for (int j=0;j<4;j++) qp_lds[w][lk*4+j][272+lm] = 0;
  #pragma unroll
  for (int j=0;j<4;j++){
    #pragma unroll
    for (int s=1;s<16;s<<=1) den[j] += __shfl_xor(den[j], s);
  }
  __syncthreads();
  f32x4 o[4] = {{0,0,0,0},{0,0,0,0},{0,0,0,0},{0,0,0,0}};
  #pragma unroll
  for (int ks=0;ks<9;++ks){
    bf16x8 av = *(const bf16x8*)&qp_lds[w][lm][ks*32 + lk*8];
    #pragma unroll
    for (int dt=0;dt<4;++dt){
      bf16x8 bv = *(const bf16x8*)(ctxT + (size_t)(h*64 + dt*16 + lm)*MP + ks*32 + lk*8);
      o[dt] = MFMA16(av, bv, o[dt]);
    }
  }
  #pragma unroll
  for (int j=0;j<4;j++){
    const int node = nb + lk*4 + j;
    if (node < n){
      const float dv = 1.f/den[j];
      #pragma unroll
      for (int dt=0;dt<4;++dt)
        trans[(size_t)node*256 + h*64 + dt*16 + lm] = f2bf(o[dt][j]*dv);
    }
  }
}

// ---------------- K5: cat -> elu -> lin2 -> elu (MFMA) ----------------
__global__ __launch_bounds__(256) void k_gnn2(
    const u16* __restrict__ G1, const u16* __restrict__ trans,
    const u16* __restrict__ l2wb, const float* __restrict__ l2b,
    float* __restrict__ G2, u16* __restrict__ xb0, int n)
{
  __shared__ u32 cat[64*256];   // 64 nodes x 512 bf16 (256 words/row), swizzled
  const int tid = threadIdx.x;
  const int w = tid>>6, l = tid&63;
  const int lm = l&15, lk = l>>4;
  const int n0 = blockIdx.x*64;
  #pragma unroll
  for (int src=0; src<2; ++src){
    const u16* S = src ? trans : G1;
    #pragma unroll
    for (int q=0;q<8;++q){
      int idx = q*256 + tid;
      int row = idx>>5, v8 = idx&31;
      int rr = n0+row; if (rr > n-1) rr = n-1;
      uint4 raw = *(const uint4*)(S + (size_t)rr*256 + v8*8);
      const u16* p = (const u16*)&raw;
      u32 o2[4];
      #pragma unroll
      for (int t2=0;t2<4;++t2)
        o2[t2] = pack2bf(eluf(bf2f(p[t2*2])), eluf(bf2f(p[t2*2+1])));
      int word = (v8*4 + src*128) ^ ((row&7)<<2);
      *(uint4*)&cat[row*256 + word] = *(uint4*)o2;
    }
  }
  __syncthreads();
  f32x4 acc[2] = {{0,0,0,0},{0,0,0,0}};
  const int rowl = w*16 + lm;
  #pragma unroll 4
  for (int kt=0; kt<16; ++kt){
    bf16x8 a = *(const bf16x8*)&cat[rowl*256 + ((kt*16 + lk*4) ^ ((rowl&7)<<2))];
    #pragma unroll
    for (int jj=0;jj<2;++jj){
      bf16x8 b = *(const bf16x8*)(l2wb + (size_t)(jj*16+lm)*512 + kt*32 + lk*8);
      acc[jj] = MFMA16(a, b, acc[jj]);
    }
  }
  #pragma unroll
  for (int jj=0;jj<2;++jj){
    const int o = jj*16 + lm;
    const float bias = l2b[o];
    #pragma unroll
    for (int jr=0;jr<4;++jr){
      const int node = n0 + w*16 + lk*4 + jr;
      if (node < n){
        float v = eluf(acc[jj][jr] + bias);
        G2[(size_t)node*32 + o] = v;
        xb0[(size_t)node*32 + o] = f2bf(v);
      }
    }
  }
}

// ---------------- edge layout detect ----------------
__global__ void k_edgemode(const int* __restrict__ ei, int* __restrict__ mode){
  __shared__ int any;
  if (threadIdx.x==0) any = 0;
  __syncthreads();
  if (ei[threadIdx.x*2+1] != 0) any = 1;
  __syncthreads();
  if (threadIdx.x==0) *mode = any;
}
__device__ __forceinline__ int edge_at(const int* ei, int mode, size_t idx){
  if (mode) return ei[idx];
  return (int)((const long long*)ei)[idx];
}

// ---------------- CSR build ----------------
__global__ void k_hist(const int* __restrict__ ei, const int* __restrict__ mode,
                       u32* __restrict__ deg, int e){
  const int md = *mode;
  for (size_t i = (size_t)blockIdx.x*blockDim.x + threadIdx.x; i < (size_t)e; i += (size_t)gridDim.x*blockDim.x)
    atomicAdd(&deg[edge_at(ei, md, (size_t)e + i)], 1u);
}
__global__ void k_dis(const u32* __restrict__ deg, float* __restrict__ dis, int n){
  int i = blockIdx.x*256 + threadIdx.x;
  if (i<n) dis[i] = rsqrtf((float)(deg[i] + 1u));
}
__global__ __launch_bounds__(1024) void k_scan(const u32* __restrict__ deg, u32* __restrict__ rowp, int n){
  __shared__ u32 wsum[16];
  __shared__ u32 carry;
  const int tid = threadIdx.x, lane = tid&63, wv = tid>>6;
  if (tid==0){ carry = 0u; rowp[0] = 0u; }
  __syncthreads();
  for (int base=0; base<n; base+=1024){
    int i = base + tid;
    u32 v = (i<n)? deg[i] : 0u;
    u32 s = v;
    #pragma unroll
    for (int off=1; off<64; off<<=1){
      u32 t = __shfl_up(s, off, 64);
      if (lane >= off) s += t;
    }
    if (lane==63) wsum[wv] = s;
    __syncthreads();
    if (wv==0){
      u32 ws = (lane<16)? wsum[lane] : 0u;
      #pragma unroll
      for (int off=1; off<16; off<<=1){
        u32 t = __shfl_up(ws, off, 64);
        if (lane >= off) ws += t;
      }
      if (lane<16) wsum[lane] = ws;
    }
    __syncthreads();
    u32 pre = carry + (wv ? wsum[wv-1] : 0u);
    if (i<n) rowp[i+1] = pre + s;
    __syncthreads();
    if (tid==0) carry += wsum[15];
    __syncthreads();
  }
}
__global__ void k_copy(const u32* __restrict__ a, u32* __restrict__ b, int n){
  int i = blockIdx.x*256 + threadIdx.x; if (i<n) b[i]=a[i];
}
__global__ void k_fill(const int* __restrict__ ei, const int* __restrict__ mode,
                       const float* __restrict__ dis,
                       u32* __restrict__ cur, uint2* __restrict__ cw, int e){
  const int md = *mode;
  for (size_t i = (size_t)blockIdx.x*blockDim.x + threadIdx.x; i < (size_t)e; i += (size_t)gridDim.x*blockDim.x){
    int s = edge_at(ei, md, i);
    int t = edge_at(ei, md, (size_t)e + i);
    u32 pos = atomicAdd(&cur[t], 1u);
    cw[pos] = make_uint2((u32)s, __float_as_uint(dis[s]*dis[t]));
  }
}

// ---------------- APPNP iteration (bf16 x, packed col+wgt) ----------------
__global__ __launch_bounds__(256) void k_appnp(
    const u16* __restrict__ xin, const float* __restrict__ hbuf,
    u16* __restrict__ xout, const u32* __restrict__ rowp,
    const uint2* __restrict__ cw, const float* __restrict__ dis, int n)
{
  const int g = threadIdx.x>>5, j = threadIdx.x&31;
  const int node = blockIdx.x*8 + g;
  if (node >= n) return;
  float d0 = dis[node];
  float acc = d0*d0*bf2f(xin[((size_t)node<<5) + j]);
  u32 r0 = rowp[node], r1 = rowp[node+1];
  u32 k = r0;
  for (; k+2 <= r1; k += 2){
    uint2 a = cw[k], b = cw[k+1];
    float xa = bf2f(xin[((size_t)a.x<<5) + j]);
    float xb = bf2f(xin[((size_t)b.x<<5) + j]);
    acc += __uint_as_float(a.y)*xa;
    acc += __uint_as_float(b.y)*xb;
  }
  if (k < r1){
    uint2 a = cw[k];
    acc += __uint_as_float(a.y)*bf2f(xin[((size_t)a.x<<5) + j]);
  }
  xout[((size_t)node<<5)+j] = f2bf(0.9f*acc + 0.1f*hbuf[((size_t)node<<5)+j]);
}

// ---------------- log_softmax + raw ----------------
__global__ __launch_bounds__(256) void k_lsm(const u16* __restrict__ xin, float* __restrict__ out, int n){
  const int g = threadIdx.x>>5, j = threadIdx.x&31;
  const int node = blockIdx.x*8 + g;
  if (node>=n) return;
  float v = bf2f(xin[((size_t)node<<5)+j]);
  float m = v;
  #pragma unroll
  for (int o=16;o;o>>=1) m = fmaxf(m, __shfl_xor(m, o, 32));
  float s = expf(v - m);
  #pragma unroll
  for (int o=16;o;o>>=1) s += __shfl_xor(s, o, 32);
  out[((size_t)node<<5)+j] = v - m - logf(s);
  out[(size_t)n*32 + ((size_t)node<<5)+j] = v;
}

extern "C" void kernel_launch(void* const* d_in, const int* in_sizes, int n_in,
                              void* d_out, int out_size, void* d_ws, size_t ws_size,
                              hipStream_t stream)
{
  const float* x   = (const float*)d_in[0];
  const int*   ei  = (const int*)  d_in[1];
  const float* l1w = (const float*)d_in[2];
  const float* l1b = (const float*)d_in[3];
  const float* l2w = (const float*)d_in[4];
  const float* l2b = (const float*)d_in[5];
  const float* qw  = (const float*)d_in[6];
  const float* qb  = (const float*)d_in[7];
  const float* kw  = (const float*)d_in[8];
  const float* kb  = (const float*)d_in[9];
  const float* vw  = (const float*)d_in[10];
  const float* vb  = (const float*)d_in[11];
  const float* proj= (const float*)d_in[12];
  const int n = in_sizes[0] / 256;
  const int e = in_sizes[1] / 2;

  char* ws = (char*)d_ws;
  auto au = [](size_t v){ return (v + 255) & ~(size_t)255; };
  const size_t bQ = (size_t)n * 512;
  const size_t oQ = 0;
  const size_t oK = au(oQ + bQ);
  const size_t oV = au(oK + bQ);
  const size_t oG1 = au(oV + bQ);
  const size_t oCtxp = au(oG1 + bQ);
  const size_t bCtxp = (size_t)NH*NB*MP*64*4;
  const size_t oKsump = au(oCtxp + bCtxp);
  const size_t bKsump = (size_t)NH*NB*MP*4;
  const size_t oCtxT = au(oKsump + bKsump);
  const size_t oKsum = au(oCtxT + (size_t)NH*64*MP*2);
  const size_t oKmax = au(oKsum + (size_t)NH*MP*4);
  const size_t oVcs  = oKmax + 256;
  const size_t oMode = oVcs + 1024;
  const size_t oL2wb = au(oMode + 256);
  const size_t oWb   = au(oL2wb + 32768);
  const size_t oProjp= au(oWb + (size_t)1024*256*2);
  // aliases: trans -> K region (K dead after k_ctx); G2/xb/appnp scratch -> Q region
  const size_t oTrans = oK;
  const size_t oG2 = oQ;
  const size_t oXb0 = au(oG2 + (size_t)n*32*4);
  const size_t oXbA = au(oXb0 + (size_t)n*32*2);
  const size_t oXbB = au(oXbA + (size_t)n*32*2);
  const size_t oDeg = au(oXbB + (size_t)n*32*2);
  const size_t oDis = au(oDeg + (size_t)n*4);
  const size_t oRowp= au(oDis + (size_t)n*4);
  const size_t oCur = au(oRowp + (size_t)(n+1)*4);
  const size_t oCw  = oV;     // uint2 per edge, V dead after k_ctx/k_vcs
  (void)ws_size; (void)n_in; (void)out_size;

  u16* Q  = (u16*)(ws + oQ);
  u16* Kb = (u16*)(ws + oK);
  u16* Vb = (u16*)(ws + oV);
  u16* G1 = (u16*)(ws + oG1);
  float* ctxp = (float*)(ws + oCtxp);
  float* ksump= (float*)(ws + oKsump);
  u16*  ctxT  = (u16*)(ws + oCtxT);
  float* ksum = (float*)(ws + oKsum);
  u32*  kmax  = (u32*)(ws + oKmax);
  float* Vcs  = (float*)(ws + oVcs);
  int*  mode  = (int*)(ws + oMode);
  u16*  l2wb  = (u16*)(ws + oL2wb);
  u16*  Wb    = (u16*)(ws + oWb);
  u16*  projp = (u16*)(ws + oProjp);
  u16* trans  = (u16*)(ws + oTrans);
  float* G2   = (float*)(ws + oG2);
  u16* xb0    = (u16*)(ws + oXb0);
  u16* xbA    = (u16*)(ws + oXbA);
  u16* xbB    = (u16*)(ws + oXbB);
  u32* deg    = (u32*)(ws + oDeg);
  float* dis  = (float*)(ws + oDis);
  u32* rowp   = (u32*)(ws + oRowp);
  u32* cur    = (u32*)(ws + oCur);
  uint2* cw   = (uint2*)(ws + oCw);

  k_cvtw<<<1024,256,0,stream>>>(qw,kw,vw,l1w,l2w,proj,Wb,projp,l2wb);
  k_proj<<<(n+127)/128,512,0,stream>>>(x,Wb,qb,kb,vb,l1b,Q,Kb,Vb,G1,n);
  hipMemsetAsync(ws + oKmax, 0, 16, stream);
  hipMemsetAsync(ws + oVcs, 0, 1024, stream);
  k_vcs<<<dim3(64,4),256,0,stream>>>(Vb,Vcs,n);
  k_ctx<<<dim3(NB,NH),256,0,stream>>>(Kb,Vb,projp,ctxp,ksump,kmax,n);
  {
    int tot = NH*MP*64 + NH*MP;
    k_reduce<<<(tot+255)/256,256,0,stream>>>(ctxp,ksump,kmax,Vcs,ctxT,ksum,n);
  }
  k_qattn<<<dim3((n+63)/64,4),256,0,stream>>>(Q,projp,ctxT,ksum,trans,n);
  k_gnn2<<<(n+63)/64,256,0,stream>>>(G1,trans,l2wb,l2b,G2,xb0,n);
  // ---- APPNP ----
  k_edgemode<<<1,256,0,stream>>>(ei,mode);
  hipMemsetAsync(ws + oDeg, 0, (size_t)n*4, stream);
  k_hist<<<2048,256,0,stream>>>(ei,mode,deg,e);
  k_dis<<<(n+255)/256,256,0,stream>>>(deg,dis,n);
  k_scan<<<1,1024,0,stream>>>(deg,rowp,n);
  k_copy<<<(n+255)/256,256,0,stream>>>(rowp,cur,n);
  k_fill<<<2048,256,0,stream>>>(ei,mode,dis,cur,cw,e);
  const u16* curx = xb0;
  u16* bufs[2] = {xbA, xbB};
  for (int it=0; it<10; ++it){
    u16* nxt = bufs[it&1];
    k_appnp<<<(n+7)/8,256,0,stream>>>(curx,G2,nxt,rowp,cw,dis,n);
    curx = nxt;
  }
  k_lsm<<<(n+7)/8,256,0,stream>>>(curx,(float*)d_out,n);
}

// Round 6
// 1521.723 us; speedup vs baseline: 3.2166x; 1.3485x over previous
//
#include <hip/hip_runtime.h>
#include <hip/hip_fp16.h>

#define NH 4
#define HD 64
#define MF 266
#define MP 288           // MF padded to multiple of 32 for MFMA K-steps
#define NB 192           // k_ctx partial blocks
#define NBQ 128          // k_qattn blocks per head (grid-stride)
#define DN 0.35355339059327373f
#define RATIO 0.06131393394849658f
#define EPSRF 1e-4f
#define REPS (RATIO*EPSRF)

typedef unsigned short u16;
typedef unsigned int u32;
typedef __attribute__((ext_vector_type(8))) short bf16x8;
typedef __attribute__((ext_vector_type(4))) float f32x4;
#define MFMA16(a,b,c) __builtin_amdgcn_mfma_f32_16x16x32_bf16(a,b,c,0,0,0)

__device__ __forceinline__ float bf2f(u16 u){ return __uint_as_float(((u32)u)<<16); }
__device__ __forceinline__ u16 f2bf(float f){ u32 u = __float_as_uint(f); u += 0x7FFFu + ((u>>16)&1u); return (u16)(u>>16); }
__device__ __forceinline__ u32 pack2bf(float a, float b){ return ((u32)f2bf(b)<<16) | f2bf(a); }
__device__ __forceinline__ float eluf(float x){ return x>0.f ? x : (expf(x)-1.f); }

// ---------------- weight/proj conversion to bf16 ----------------
__global__ void k_cvtw(const float* __restrict__ qw, const float* __restrict__ kw,
                       const float* __restrict__ vw, const float* __restrict__ lw,
                       const float* __restrict__ l2w, const float* __restrict__ proj,
                       u16* __restrict__ Wb, u16* __restrict__ projp, u16* __restrict__ l2wb){
  int i = blockIdx.x*256 + threadIdx.x;
  if (i < 262144){
    int sec = i>>16, r = i&65535;
    const float* s = sec==0?qw : sec==1?kw : sec==2?vw : lw;
    Wb[i] = f2bf(s[r]);
  }
  if (i < MP*64){
    int r = i>>6, c = i&63;
    projp[i] = f2bf(r < MF ? proj[r*64 + c] : 0.f);
  }
  if (i < 32*512) l2wb[i] = f2bf(l2w[i]);
}

// ---------------- K1: fused projection GEMM (MFMA, X staged once, 8 waves) ----------------
__global__ __launch_bounds__(512,4) void k_proj(
    const float* __restrict__ x, const u16* __restrict__ Wb,
    const float* __restrict__ qb, const float* __restrict__ kb,
    const float* __restrict__ vb, const float* __restrict__ lb,
    u16* __restrict__ Q, u16* __restrict__ K, u16* __restrict__ V,
    u16* __restrict__ G1, int n)
{
  __shared__ u32 Xs[128*128];   // [row][word 0..127], XOR-swizzled
  const int tid = threadIdx.x;
  const int w = tid>>6, l = tid&63;
  const int wr = w>>2, wc = w&3;
  const int lm = l&15, lk = l>>4;
  const int row0 = blockIdx.x*128;
  #pragma unroll 4
  for (int q=0;q<16;++q){
    int idx = q*512 + tid;
    int r = idx>>6, c4 = idx&63;
    int rr = row0 + r; if (rr > n-1) rr = n-1;
    float4 v = *(const float4*)(x + (size_t)rr*256 + c4*4);
    int word = (c4*2) ^ ((r&7)<<2);
    *(uint2*)&Xs[r*128 + word] = make_uint2(pack2bf(v.x,v.y), pack2bf(v.z,v.w));
  }
  __syncthreads();
  #pragma unroll 1
  for (int ct=0; ct<8; ++ct){
    const int c0 = ct*128 + wc*32;
    f32x4 acc[4][2] = {};
    #pragma unroll 2
    for (int kt=0; kt<8; ++kt){
      bf16x8 Af[4], Bf[2];
      #pragma unroll
      for (int jj=0;jj<2;jj++)
        Bf[jj] = *(const bf16x8*)(Wb + (size_t)(c0 + jj*16 + lm)*256 + kt*32 + lk*8);
      #pragma unroll
      for (int i=0;i<4;i++){
        const int rl = wr*64 + i*16 + lm;
        Af[i] = *(const bf16x8*)&Xs[rl*128 + ((kt*16 + lk*4) ^ ((rl&7)<<2))];
      }
      #pragma unroll
      for (int i=0;i<4;i++)
        #pragma unroll
        for (int jj=0;jj<2;jj++)
          acc[i][jj] = MFMA16(Af[i], Bf[jj], acc[i][jj]);
    }
    const int sel = c0>>8;
    const float* bp = sel==0?qb : sel==1?kb : sel==2?vb : lb;
    u16* d3 = sel==0?Q : sel==1?K : sel==2?V : G1;
    u32* dst32 = (u32*)d3;
    const bool even = (lm&1)==0;
    #pragma unroll
    for (int jj=0;jj<2;jj++){
      const int cc = (c0&255) + jj*16 + lm;
      const float bias = bp[cc];
      const int ccA = cc & ~1;
      const int hh = ccA>>6, dd = ccA&63;
      #pragma unroll
      for (int i=0;i<4;i++){
        const int rb = row0 + wr*64 + i*16 + lk*4;
        u32 m01 = pack2bf(acc[i][jj][0]+bias, acc[i][jj][1]+bias);
        u32 m23 = pack2bf(acc[i][jj][2]+bias, acc[i][jj][3]+bias);
        u32 oa = __shfl_xor(m01,1);
        u32 ob = __shfl_xor(m23,1);
        u32 wA = even ? ((m01 & 0xffffu) | ((oa & 0xffffu)<<16))
                      : ((ob  & 0xffffu) | ((m23 & 0xffffu)<<16));
        u32 wB = even ? ((m01 >> 16) | (oa & 0xffff0000u))
                      : ((ob  >> 16) | (m23 & 0xffff0000u));
        const int rA = rb + (even ? 0 : 2);
        const int rB = rA + 1;
        if (sel==3){
          if (rA < n) dst32[(size_t)rA*128 + (ccA>>1)] = wA;
          if (rB < n) dst32[(size_t)rB*128 + (ccA>>1)] = wB;
        } else {
          if (rA < n) dst32[(((size_t)hh*n + rA)<<5) + (dd>>1)] = wA;
          if (rB < n) dst32[(((size_t)hh*n + rB)<<5) + (dd>>1)] = wB;
        }
      }
    }
  }
}

// ---------------- V column sums (for EPS correction) ----------------
__global__ void k_vcs(const u16* __restrict__ Vb, float* __restrict__ vcs, int n){
  const int h = blockIdx.y, tid = threadIdx.x;
  const int d = tid&63, seg = tid>>6;
  float s = 0.f;
  for (int node = blockIdx.x*4 + seg; node < n; node += 256)
    s += bf2f(Vb[(((size_t)h*n + node)<<6) + d]);
  __shared__ float sm[4][64];
  sm[seg][d] = s; __syncthreads();
  if (tid < 64){
    float t2 = sm[0][tid]+sm[1][tid]+sm[2][tid]+sm[3][tid];
    atomicAdd(vcs + h*64 + tid, t2);
  }
}

// ---------------- K3: single-pass kp -> ksum0/ctx0 partials + global dash max ----------------
__global__ __launch_bounds__(256) void k_ctx(
    const u16* __restrict__ Kb, const u16* __restrict__ Vb,
    const u16* __restrict__ projp,
    float* __restrict__ ctxp, float* __restrict__ ksump,
    u32* __restrict__ kmaxg, int n)
{
  __shared__ u32 kpT[288*32];     // kp^T [m][node-word], XOR-swizzled
  __shared__ u16 Vt[64][72];      // V^T tile [d][node]
  __shared__ float redk[4][288];
  const int tid = threadIdx.x;
  const int w = tid>>6, l = tid&63;
  const int bb = blockIdx.x;
  const int h = blockIdx.y;
  const int lm = l&15, lk = l>>4;
  f32x4 cacc[18] = {};
  float ksa[18] = {};
  float mreg = -3.0e38f;
  const int ntile = (n+63)>>6;
  #pragma unroll 1
  for (int t=bb; t<ntile; t+=NB){
    const int n0 = t*64;
    __syncthreads();
    #pragma unroll
    for (int q=0;q<2;q++){
      int e8 = tid + q*256;
      int nn = e8>>3, d0 = (e8&7)*8;
      uint4 rv = make_uint4(0,0,0,0);
      if (n0+nn < n) rv = *(const uint4*)(Vb + (((size_t)h*n + n0+nn)<<6) + d0);
      const u16* pv = (const u16*)&rv;
      #pragma unroll
      for (int s=0;s<8;s++) Vt[d0+s][nn] = pv[s];
    }
    int rr = n0 + w*16 + lm; if (rr > n-1) rr = n-1;
    const u16* Kbase = Kb + (((size_t)h*n + rr)<<6);
    bf16x8 af0 = *(const bf16x8*)(Kbase + lk*8);
    bf16x8 af1 = *(const bf16x8*)(Kbase + 32 + lk*8);
    float dg = 0.f;
    #pragma unroll
    for (int i2=0;i2<8;i2++){
      float a = bf2f(((const u16*)&af0)[i2]);
      float b = bf2f(((const u16*)&af1)[i2]);
      dg += a*a + b*b;
    }
    dg += __shfl_xor(dg,16); dg += __shfl_xor(dg,32);
    dg *= 0.0625f;
    float dgr[4];
    #pragma unroll
    for (int j=0;j<4;j++) dgr[j] = __shfl(dg, lk*4+j, 16);
    #pragma unroll
    for (int mt=0; mt<18; ++mt){
      bf16x8 b0 = *(const bf16x8*)(projp + (size_t)(mt*16+lm)*64 + lk*8);
      bf16x8 b1 = *(const bf16x8*)(projp + (size_t)(mt*16+lm)*64 + 32 + lk*8);
      f32x4 D = {0,0,0,0};
      D = MFMA16(af0, b0, D);
      D = MFMA16(af1, b1, D);
      const int m = mt*16 + lm;
      const bool vm = m < MF;
      float colsum = 0.f;
      u32 pk0 = 0, pk1 = 0;
      #pragma unroll
      for (int j=0;j<4;j++){
        float ddash = DN * D[j];
        float kp = 0.f;
        if (vm && (n0 + w*16 + lk*4 + j) < n){
          kp = RATIO * __expf(ddash - dgr[j]);
          mreg = fmaxf(mreg, ddash);
          colsum += kp;
        }
        if (j<2) pk0 |= ((u32)f2bf(kp)) << (16*j);
        else     pk1 |= ((u32)f2bf(kp)) << (16*(j-2));
      }
      const int wn0 = w*8 + lk*2;
      *(uint2*)&kpT[m*32 + (wn0 ^ ((m&7)<<2))] = make_uint2(pk0, pk1);
      colsum += __shfl_xor(colsum,16); colsum += __shfl_xor(colsum,32);
      ksa[mt] += colsum;
    }
    __syncthreads();
    #pragma unroll
    for (int mt=0; mt<18; ++mt){
      const int m = mt*16 + lm;
      #pragma unroll
      for (int ks=0;ks<2;++ks){
        bf16x8 a = *(const bf16x8*)&kpT[m*32 + ((ks*16 + lk*4) ^ ((m&7)<<2))];
        bf16x8 bv = *(const bf16x8*)&Vt[w*16+lm][ks*32 + lk*8];
        cacc[mt] = MFMA16(a, bv, cacc[mt]);
      }
    }
  }
  float* cp = ctxp + ((size_t)(h*NB + bb))*MP*64;
  #pragma unroll
  for (int mt=0;mt<18;++mt){
    #pragma unroll
    for (int j=0;j<4;j++){
      int m = mt*16 + lk*4 + j;
      cp[(size_t)m*64 + w*16 + lm] = cacc[mt][j];
    }
  }
  if (l < 16){
    #pragma unroll
    for (int mt=0;mt<18;++mt) redk[w][mt*16+lm] = ksa[mt];
  }
  __shared__ float redm[4];
  float mr = mreg;
  #pragma unroll
  for (int s=1;s<64;s<<=1) mr = fmaxf(mr, __shfl_xor(mr, s));
  if (l==0) redm[w] = mr;
  __syncthreads();
  for (int m2=tid; m2<MP; m2+=256){
    float s = redk[0][m2]+redk[1][m2]+redk[2][m2]+redk[3][m2];
    ksump[((size_t)(h*NB+bb))*MP + m2] = s;
  }
  if (tid==0){
    float bm = fmaxf(fmaxf(redm[0],redm[1]), fmaxf(redm[2],redm[3]));
    u32 b = __float_as_uint(bm);
    u32 enc = (b & 0x80000000u) ? ~b : (b | 0x80000000u);
    atomicMax(kmaxg + h, enc);
  }
}

// ---------------- K3b: reduce partials + apply max/EPS correction ----------------
__global__ void k_reduce(const float* __restrict__ ctxp, const float* __restrict__ ksump,
                         const u32* __restrict__ kmaxg, const float* __restrict__ vcs,
                         u16* __restrict__ ctxT, float* __restrict__ ksum, int n)
{
  const int T1 = NH*MP*64;
  int idx = blockIdx.x*256 + threadIdx.x;
  if (idx < T1){
    int h = idx/(MP*64), r = idx - h*MP*64, m = r>>6, d = r&63;
    u32 ee = kmaxg[h]; u32 b = (ee & 0x80000000u) ? (ee ^ 0x80000000u) : ~ee;
    float sc = __expf(-__uint_as_float(b));
    float s = 0.f;
    for (int bb=0; bb<NB; ++bb) s += ctxp[(((size_t)(h*NB+bb))*MP + m)*64 + d];
    float val = (m < MF) ? (sc*s + REPS*vcs[h*64 + d]) : 0.f;
    ctxT[((size_t)h*64 + d)*MP + m] = f2bf(val);
  } else if (idx < T1 + NH*MP){
    int k2 = idx - T1, h = k2/MP, m = k2 - h*MP;
    u32 ee = kmaxg[h]; u32 b = (ee & 0x80000000u) ? (ee ^ 0x80000000u) : ~ee;
    float sc = __expf(-__uint_as_float(b));
    float s = 0.f;
    for (int bb=0; bb<NB; ++bb) s += ksump[((size_t)(h*NB+bb))*MP + m];
    ksum[h*MP + m] = (m < MF) ? (sc*s + REPS*(float)n) : 0.f;
  }
}

// ---------------- K4: query path (MFMA, proj staged in LDS, grid-stride tiles) ----------------
__global__ __launch_bounds__(256) void k_qattn(
    const u16* __restrict__ Qb, const u16* __restrict__ projp,
    const u16* __restrict__ ctxT, const float* __restrict__ ksum,
    u16* __restrict__ trans, int n)
{
  __shared__ u32 pj[288*32];              // swizzled proj (36864 B)
  __shared__ u16 qp_lds[4][16][168];      // per-wave qp half (21504 B)
  const int tid = threadIdx.x;
  const int w = tid>>6, l = tid&63;
  const int h = blockIdx.y;
  const int lm = l&15, lk = l>>4;
  // stage proj once (coalesced, swizzled)
  #pragma unroll
  for (int q=0; q<9; ++q){
    int cix = q*256 + tid;                // 2304 16B-chunks
    int row = cix>>3, c4 = (cix&7)*4;
    uint4 v = *(const uint4*)(projp + row*64 + c4*2);
    *(uint4*)&pj[row*32 + (c4 ^ ((row&7)<<2))] = v;
  }
  float ksm[18];
  #pragma unroll
  for (int mt=0;mt<18;++mt) ksm[mt] = ksum[h*MP + mt*16 + lm];
  __syncthreads();
  const int ntile = (n+63)>>6;
  #pragma unroll 1
  for (int t = blockIdx.x; t < ntile; t += NBQ){
    const int nb = t*64 + w*16;
    int rr = nb + lm; if (rr > n-1) rr = n-1;
    const u16* Qbase = Qb + (((size_t)h*n + rr)<<6);
    bf16x8 af0 = *(const bf16x8*)(Qbase + lk*8);
    bf16x8 af1 = *(const bf16x8*)(Qbase + 32 + lk*8);
    float dg = 0.f;
    #pragma unroll
    for (int i2=0;i2<8;i2++){
      float a = bf2f(((const u16*)&af0)[i2]);
      float b = bf2f(((const u16*)&af1)[i2]);
      dg += a*a + b*b;
    }
    dg += __shfl_xor(dg,16); dg += __shfl_xor(dg,32);
    dg *= 0.0625f;
    float dgr[4];
    #pragma unroll
    for (int j=0;j<4;j++) dgr[j] = __shfl(dg, lk*4+j, 16);
    // dash: all 18 m-tiles, B from LDS
    f32x4 D[18];
    #pragma unroll
    for (int mt=0;mt<18;++mt){
      const int m = mt*16 + lm;
      bf16x8 b0 = *(const bf16x8*)&pj[m*32 + ((lk*4) ^ ((m&7)<<2))];
      bf16x8 b1 = *(const bf16x8*)&pj[m*32 + ((16 + lk*4) ^ ((m&7)<<2))];
      f32x4 z = {0,0,0,0};
      z = MFMA16(af0, b0, z);
      z = MFMA16(af1, b1, z);
      D[mt] = z;
    }
    // row max over valid m (<MF)
    float rmax[4] = {-3.0e38f,-3.0e38f,-3.0e38f,-3.0e38f};
    #pragma unroll
    for (int mt=0;mt<17;++mt){
      const bool vm = (mt<16) || (lm<10);
      #pragma unroll
      for (int j=0;j<4;j++){
        float dd = DN*D[mt][j];
        if (vm) rmax[j] = fmaxf(rmax[j], dd);
      }
    }
    #pragma unroll
    for (int j=0;j<4;j++){
      #pragma unroll
      for (int s=1;s<16;s<<=1) rmax[j] = fmaxf(rmax[j], __shfl_xor(rmax[j], s));
    }
    float den[4] = {0,0,0,0};
    f32x4 o[4] = {{0,0,0,0},{0,0,0,0},{0,0,0,0},{0,0,0,0}};
    // ---- half 0: m 0..159 ----
    #pragma unroll
    for (int mt=0;mt<10;++mt){
      #pragma unroll
      for (int j=0;j<4;j++){
        float qp = RATIO*(__expf(DN*D[mt][j] - dgr[j] - rmax[j]) + EPSRF);
        den[j] += qp * ksm[mt];
        qp_lds[w][lk*4+j][mt*16+lm] = f2bf(qp);
      }
    }
    #pragma unroll
    for (int ks=0;ks<5;++ks){
      bf16x8 av = *(const bf16x8*)&qp_lds[w][lm][ks*32 + lk*8];
      #pragma unroll
      for (int dt=0;dt<4;++dt){
        bf16x8 bv = *(const bf16x8*)(ctxT + (size_t)(h*64 + dt*16 + lm)*MP + ks*32 + lk*8);
        o[dt] = MFMA16(av, bv, o[dt]);
      }
    }
    // ---- half 1: m 160..287 ----
    #pragma unroll
    for (int mt=10;mt<18;++mt){
      #pragma unroll
      for (int j=0;j<4;j++){
        float qp = RATIO*(__expf(DN*D[mt][j] - dgr[j] - rmax[j]) + EPSRF);
        den[j] += qp * ksm[mt];
        qp_lds[w][lk*4+j][(mt-10)*16+lm] = f2bf(qp);
      }
    }
    #pragma unroll
    for (int ks=5;ks<9;++ks){
      bf16x8 av = *(const bf16x8*)&qp_lds[w][lm][(ks-5)*32 + lk*8];
      #pragma unroll
      for (int dt=0;dt<4;++dt){
        bf16x8 bv = *(const bf16x8*)(ctxT + (size_t)(h*64 + dt*16 + lm)*MP + ks*32 + lk*8);
        o[dt] = MFMA16(av, bv, o[dt]);
      }
    }
    #pragma unroll
    for (int j=0;j<4;j++){
      #pragma unroll
      for (int s=1;s<16;s<<=1) den[j] += __shfl_xor(den[j], s);
    }
    #pragma unroll
    for (int j=0;j<4;j++){
      const int node = nb + lk*4 + j;
      if (node < n){
        const float dv = 1.f/den[j];
        #pragma unroll
        for (int dt=0;dt<4;++dt)
          trans[(size_t)node*256 + h*64 + dt*16 + lm] = f2bf(o[dt][j]*dv);
      }
    }
  }
}

// ---------------- K5: cat -> elu -> lin2 -> elu (MFMA) ----------------
__global__ __launch_bounds__(256) void k_gnn2(
    const u16* __restrict__ G1, const u16* __restrict__ trans,
    const u16* __restrict__ l2wb, const float* __restrict__ l2b,
    u16* __restrict__ xb0, int n)
{
  __shared__ u32 cat[64*256];   // 64 nodes x 512 bf16, swizzled
  const int tid = threadIdx.x;
  const int w = tid>>6, l = tid&63;
  const int lm = l&15, lk = l>>4;
  const int n0 = blockIdx.x*64;
  #pragma unroll
  for (int src=0; src<2; ++src){
    const u16* S = src ? trans : G1;
    #pragma unroll
    for (int q=0;q<8;++q){
      int idx = q*256 + tid;
      int row = idx>>5, v8 = idx&31;
      int rr = n0+row; if (rr > n-1) rr = n-1;
      uint4 raw = *(const uint4*)(S + (size_t)rr*256 + v8*8);
      const u16* p = (const u16*)&raw;
      u32 o2[4];
      #pragma unroll
      for (int t2=0;t2<4;++t2)
        o2[t2] = pack2bf(eluf(bf2f(p[t2*2])), eluf(bf2f(p[t2*2+1])));
      int word = (v8*4 + src*128) ^ ((row&7)<<2);
      *(uint4*)&cat[row*256 + word] = *(uint4*)o2;
    }
  }
  __syncthreads();
  f32x4 acc[2] = {{0,0,0,0},{0,0,0,0}};
  const int rowl = w*16 + lm;
  #pragma unroll 4
  for (int kt=0; kt<16; ++kt){
    bf16x8 a = *(const bf16x8*)&cat[rowl*256 + ((kt*16 + lk*4) ^ ((rowl&7)<<2))];
    #pragma unroll
    for (int jj=0;jj<2;++jj){
      bf16x8 b = *(const bf16x8*)(l2wb + (size_t)(jj*16+lm)*512 + kt*32 + lk*8);
      acc[jj] = MFMA16(a, b, acc[jj]);
    }
  }
  #pragma unroll
  for (int jj=0;jj<2;++jj){
    const int o = jj*16 + lm;
    const float bias = l2b[o];
    #pragma unroll
    for (int jr=0;jr<4;++jr){
      const int node = n0 + w*16 + lk*4 + jr;
      if (node < n)
        xb0[(size_t)node*32 + o] = f2bf(eluf(acc[jj][jr] + bias));
    }
  }
}

// ---------------- edge layout detect ----------------
__global__ void k_edgemode(const int* __restrict__ ei, int* __restrict__ mode){
  __shared__ int any;
  if (threadIdx.x==0) any = 0;
  __syncthreads();
  if (ei[threadIdx.x*2+1] != 0) any = 1;
  __syncthreads();
  if (threadIdx.x==0) *mode = any;
}
__device__ __forceinline__ int edge_at(const int* ei, int mode, size_t idx){
  if (mode) return ei[idx];
  return (int)((const long long*)ei)[idx];
}

// ---------------- CSR build ----------------
__global__ void k_hist(const int* __restrict__ ei, const int* __restrict__ mode,
                       u32* __restrict__ deg, int e){
  const int md = *mode;
  for (size_t i = (size_t)blockIdx.x*blockDim.x + threadIdx.x; i < (size_t)e; i += (size_t)gridDim.x*blockDim.x)
    atomicAdd(&deg[edge_at(ei, md, (size_t)e + i)], 1u);
}
__global__ void k_dis(const u32* __restrict__ deg, float* __restrict__ dis, int n){
  int i = blockIdx.x*256 + threadIdx.x;
  if (i<n) dis[i] = rsqrtf((float)(deg[i] + 1u));
}
__global__ __launch_bounds__(1024) void k_scan(const u32* __restrict__ deg, u32* __restrict__ rowp, int n){
  __shared__ u32 wsum[16];
  __shared__ u32 carry;
  const int tid = threadIdx.x, lane = tid&63, wv = tid>>6;
  if (tid==0){ carry = 0u; rowp[0] = 0u; }
  __syncthreads();
  for (int base=0; base<n; base+=1024){
    int i = base + tid;
    u32 v = (i<n)? deg[i] : 0u;
    u32 s = v;
    #pragma unroll
    for (int off=1; off<64; off<<=1){
      u32 t = __shfl_up(s, off, 64);
      if (lane >= off) s += t;
    }
    if (lane==63) wsum[wv] = s;
    __syncthreads();
    if (wv==0){
      u32 ws = (lane<16)? wsum[lane] : 0u;
      #pragma unroll
      for (int off=1; off<16; off<<=1){
        u32 t = __shfl_up(ws, off, 64);
        if (lane >= off) ws += t;
      }
      if (lane<16) wsum[lane] = ws;
    }
    __syncthreads();
    u32 pre = carry + (wv ? wsum[wv-1] : 0u);
    if (i<n) rowp[i+1] = pre + s;
    __syncthreads();
    if (tid==0) carry += wsum[15];
    __syncthreads();
  }
}
__global__ void k_copy(const u32* __restrict__ a, u32* __restrict__ b, int n){
  int i = blockIdx.x*256 + threadIdx.x; if (i<n) b[i]=a[i];
}
__global__ void k_fill(const int* __restrict__ ei, const int* __restrict__ mode,
                       const float* __restrict__ dis,
                       u32* __restrict__ cur, uint2* __restrict__ cw, int e){
  const int md = *mode;
  for (size_t i = (size_t)blockIdx.x*blockDim.x + threadIdx.x; i < (size_t)e; i += (size_t)gridDim.x*blockDim.x){
    int s = edge_at(ei, md, i);
    int t = edge_at(ei, md, (size_t)e + i);
    u32 pos = atomicAdd(&cur[t], 1u);
    cw[pos] = make_uint2((u32)s, __float_as_uint(dis[s]*dis[t]));
  }
}

// ---------------- APPNP iteration (packed u32 x, 16 lanes/node, 4-unroll) ----------------
__global__ __launch_bounds__(256) void k_appnp(
    const u16* __restrict__ xin, const u16* __restrict__ hb16,
    u16* __restrict__ xout, const u32* __restrict__ rowp,
    const uint2* __restrict__ cw, const float* __restrict__ dis, int n)
{
  const int g = threadIdx.x>>4, j2 = threadIdx.x&15;
  const int node = blockIdx.x*16 + g;
  if (node >= n) return;
  const u32* x32 = (const u32*)xin;
  float d0 = dis[node];
  float dd = d0*d0;
  u32 xv = x32[((size_t)node<<4) + j2];
  float a0 = dd*bf2f((u16)xv), a1 = dd*bf2f((u16)(xv>>16));
  u32 r0 = rowp[node], r1 = rowp[node+1];
  u32 k = r0;
  for (; k+4 <= r1; k += 4){
    uint2 e0 = cw[k], e1 = cw[k+1], e2 = cw[k+2], e3 = cw[k+3];
    u32 v0 = x32[((size_t)e0.x<<4)+j2], v1 = x32[((size_t)e1.x<<4)+j2];
    u32 v2 = x32[((size_t)e2.x<<4)+j2], v3 = x32[((size_t)e3.x<<4)+j2];
    float w0=__uint_as_float(e0.y), w1=__uint_as_float(e1.y);
    float w2=__uint_as_float(e2.y), w3=__uint_as_float(e3.y);
    a0 += w0*bf2f((u16)v0) + w1*bf2f((u16)v1) + w2*bf2f((u16)v2) + w3*bf2f((u16)v3);
    a1 += w0*bf2f((u16)(v0>>16)) + w1*bf2f((u16)(v1>>16)) + w2*bf2f((u16)(v2>>16)) + w3*bf2f((u16)(v3>>16));
  }
  for (; k < r1; ++k){
    uint2 e = cw[k];
    u32 v = x32[((size_t)e.x<<4)+j2];
    float wgt = __uint_as_float(e.y);
    a0 += wgt*bf2f((u16)v);
    a1 += wgt*bf2f((u16)(v>>16));
  }
  u32 hv = ((const u32*)hb16)[((size_t)node<<4) + j2];
  ((u32*)xout)[((size_t)node<<4) + j2] =
      pack2bf(0.9f*a0 + 0.1f*bf2f((u16)hv), 0.9f*a1 + 0.1f*bf2f((u16)(hv>>16)));
}

// ---------------- log_softmax + raw ----------------
__global__ __launch_bounds__(256) void k_lsm(const u16* __restrict__ xin, float* __restrict__ out, int n){
  const int g = threadIdx.x>>5, j = threadIdx.x&31;
  const int node = blockIdx.x*8 + g;
  if (node>=n) return;
  float v = bf2f(xin[((size_t)node<<5)+j]);
  float m = v;
  #pragma unroll
  for (int o=16;o;o>>=1) m = fmaxf(m, __shfl_xor(m, o, 32));
  float s = expf(v - m);
  #pragma unroll
  for (int o=16;o;o>>=1) s += __shfl_xor(s, o, 32);
  out[((size_t)node<<5)+j] = v - m - logf(s);
  out[(size_t)n*32 + ((size_t)node<<5)+j] = v;
}

extern "C" void kernel_launch(void* const* d_in, const int* in_sizes, int n_in,
                              void* d_out, int out_size, void* d_ws, size_t ws_size,
                              hipStream_t stream)
{
  const float* x   = (const float*)d_in[0];
  const int*   ei  = (const int*)  d_in[1];
  const float* l1w = (const float*)d_in[2];
  const float* l1b = (const float*)d_in[3];
  const float* l2w = (const float*)d_in[4];
  const float* l2b = (const float*)d_in[5];
  const float* qw  = (const float*)d_in[6];
  const float* qb  = (const float*)d_in[7];
  const float* kw  = (const float*)d_in[8];
  const float* kb  = (const float*)d_in[9];
  const float* vw  = (const float*)d_in[10];
  const float* vb  = (const float*)d_in[11];
  const float* proj= (const float*)d_in[12];
  const int n = in_sizes[0] / 256;
  const int e = in_sizes[1] / 2;

  char* ws = (char*)d_ws;
  auto au = [](size_t v){ return (v + 255) & ~(size_t)255; };
  const size_t bQ = (size_t)n * 512;
  const size_t oQ = 0;
  const size_t oK = au(oQ + bQ);
  const size_t oV = au(oK + bQ);
  const size_t oG1 = au(oV + bQ);
  const size_t oCtxp = au(oG1 + bQ);
  const size_t bCtxp = (size_t)NH*NB*MP*64*4;
  const size_t oKsump = au(oCtxp + bCtxp);
  const size_t bKsump = (size_t)NH*NB*MP*4;
  const size_t oCtxT = au(oKsump + bKsump);
  const size_t oKsum = au(oCtxT + (size_t)NH*64*MP*2);
  const size_t oKmax = au(oKsum + (size_t)NH*MP*4);
  const size_t oVcs  = oKmax + 256;
  const size_t oMode = oVcs + 1024;
  const size_t oL2wb = au(oMode + 256);
  const size_t oWb   = au(oL2wb + 32768);
  const size_t oProjp= au(oWb + (size_t)1024*256*2);
  // aliases: trans -> K region (K dead after k_ctx); xb/appnp scratch -> Q region
  const size_t oTrans = oK;
  const size_t oG2 = oQ;
  const size_t oXb0 = au(oG2 + (size_t)n*32*4);
  const size_t oXbA = au(oXb0 + (size_t)n*32*2);
  const size_t oXbB = au(oXbA + (size_t)n*32*2);
  const size_t oDeg = au(oXbB + (size_t)n*32*2);
  const size_t oDis = au(oDeg + (size_t)n*4);
  const size_t oRowp= au(oDis + (size_t)n*4);
  const size_t oCur = au(oRowp + (size_t)(n+1)*4);
  const size_t oCw  = oV;     // uint2 per edge, V dead after k_ctx/k_vcs
  (void)ws_size; (void)n_in; (void)out_size;

  u16* Q  = (u16*)(ws + oQ);
  u16* Kb = (u16*)(ws + oK);
  u16* Vb = (u16*)(ws + oV);
  u16* G1 = (u16*)(ws + oG1);
  float* ctxp = (float*)(ws + oCtxp);
  float* ksump= (float*)(ws + oKsump);
  u16*  ctxT  = (u16*)(ws + oCtxT);
  float* ksum = (float*)(ws + oKsum);
  u32*  kmax  = (u32*)(ws + oKmax);
  float* Vcs  = (float*)(ws + oVcs);
  int*  mode  = (int*)(ws + oMode);
  u16*  l2wb  = (u16*)(ws + oL2wb);
  u16*  Wb    = (u16*)(ws + oWb);
  u16*  projp = (u16*)(ws + oProjp);
  u16* trans  = (u16*)(ws + oTrans);
  u16* xb0    = (u16*)(ws + oXb0);
  u16* xbA    = (u16*)(ws + oXbA);
  u16* xbB    = (u16*)(ws + oXbB);
  u32* deg    = (u32*)(ws + oDeg);
  float* dis  = (float*)(ws + oDis);
  u32* rowp   = (u32*)(ws + oRowp);
  u32* cur    = (u32*)(ws + oCur);
  uint2* cw   = (uint2*)(ws + oCw);

  k_cvtw<<<1024,256,0,stream>>>(qw,kw,vw,l1w,l2w,proj,Wb,projp,l2wb);
  k_proj<<<(n+127)/128,512,0,stream>>>(x,Wb,qb,kb,vb,l1b,Q,Kb,Vb,G1,n);
  hipMemsetAsync(ws + oKmax, 0, 16, stream);
  hipMemsetAsync(ws + oVcs, 0, 1024, stream);
  k_vcs<<<dim3(64,4),256,0,stream>>>(Vb,Vcs,n);
  k_ctx<<<dim3(NB,NH),256,0,stream>>>(Kb,Vb,projp,ctxp,ksump,kmax,n);
  {
    int tot = NH*MP*64 + NH*MP;
    k_reduce<<<(tot+255)/256,256,0,stream>>>(ctxp,ksump,kmax,Vcs,ctxT,ksum,n);
  }
  k_qattn<<<dim3(NBQ,4),256,0,stream>>>(Q,projp,ctxT,ksum,trans,n);
  k_gnn2<<<(n+63)/64,256,0,stream>>>(G1,trans,l2wb,l2b,xb0,n);
  // ---- APPNP ----
  k_edgemode<<<1,256,0,stream>>>(ei,mode);
  hipMemsetAsync(ws + oDeg, 0, (size_t)n*4, stream);
  k_hist<<<2048,256,0,stream>>>(ei,mode,deg,e);
  k_dis<<<(n+255)/256,256,0,stream>>>(deg,dis,n);
  k_scan<<<1,1024,0,stream>>>(deg,rowp,n);
  k_copy<<<(n+255)/256,256,0,stream>>>(rowp,cur,n);
  k_fill<<<2048,256,0,stream>>>(ei,mode,dis,cur,cw,e);
  const u16* curx = xb0;
  u16* bufs[2] = {xbA, xbB};
  for (int it=0; it<10; ++it){
    u16* nxt = bufs[it&1];
    k_appnp<<<(n+15)/16,256,0,stream>>>(curx,xb0,nxt,rowp,cw,dis,n);
    curx = nxt;
  }
  k_lsm<<<(n+7)/8,256,0,stream>>>(curx,(float*)d_out,n);
}